// Round 9
// baseline (506.866 us; speedup 1.0000x reference)
//
#include <hip/hip_runtime.h>
#include <math.h>

// DilatedAttention on MI355X (gfx950), bf16 MFMA implementation.
// L=4096, E=1024, H=16, D=64. Branches (sl,dr) = (1024,1),(2048,2),(4096,4).
// Every branch reduces to causal attention over g=1024 sparse positions.
//
// Attention in transposed-S form:
//   S^T = K Q^T  (lane l16 = q column)
//   O^T = V^T P^T with 16x16x16 MFMA    -> P^T registers are the B-operand.
// R4: XOR-swizzled attn LDS tiles via staging-source permutation.
// R5: q-tile PAIR (j, 15-j) per block: exactly 17 tile-computes each.
// R6: fused dual-tile compute (shared K/V fragments, interleaved chains).
// R7: GEMM/attn XCD-affinity remaps; V^T pair-permuted (bank conflicts -> 0).
// R8: attn l-sum via ones-MFMA; setprio removed (measured regression).
// R9-R11 (FAILED/NULL): reg-staged cvt fusion; T3/T4 pipelining on 128² GEMM.
// GEMM K-loop structure is frozen at the 2-barrier 16KB-era loop (42.5us).
// R12 (WIN, -10us): vtrans fused into gemm_qkv V epilogue (6 -> 5 launches);
// calibrated launch overhead ~6us/launch + dispatch time.
// R13: cvt kernel DELETED (5 -> 4 launches). GEMMs consume fp32 operands
// directly: staging stays pure global_load_lds DMA (fp32-wide, 8 gload16/
// thread, 32KB LDS); fp32->bf16 conversion moves to the FRAGMENT-READ path
// (~32 scalar cvts/wave/K-step, overlapped with MFMA issue; VALUBusy was
// 13% -- headroom). Unlike R9, no VALU/ds_write on the staging path.
// GEMM LDS swizzle deliberately NOT bundled: T2 regime gate says null on
// 2-phase structures (m230).

#define L_SEQ 4096
#define EDIM  1024
#define NH    16
#define HD    64
#define GLEN  1024

typedef __bf16 bf16;
typedef __bf16 bf16x8 __attribute__((ext_vector_type(8)));
typedef __bf16 bf16x4 __attribute__((ext_vector_type(4)));
typedef __bf16 bf16x2 __attribute__((ext_vector_type(2)));
typedef short  s16x4  __attribute__((ext_vector_type(4)));
typedef float  f32x4  __attribute__((ext_vector_type(4)));

template <bool B> struct Flag { static constexpr bool v = B; };

// async global->LDS, 16B per lane. LDS dest semantics: wave-uniform base + lane*16.
__device__ __forceinline__ void gload16v(const void* g, void* l) {
  __builtin_amdgcn_global_load_lds(
      (__attribute__((address_space(1))) void*)(const_cast<void*>(g)),
      (__attribute__((address_space(3))) void*)(l),
      16, 0, 0);
}
__device__ __forceinline__ void gload16(const bf16* g, bf16* l) {
  gload16v((const void*)g, (void*)l);
}

// v_mfma_f32_16x16x16_bf16 (builtin name only exists in the device pass).
__device__ __forceinline__ f32x4 mfma16x16x16_bf16(bf16x4 a, bf16x4 b, f32x4 c) {
#if defined(__HIP_DEVICE_COMPILE__)
  union { bf16x4 h; s16x4 s; } ua, ub;
  ua.h = a; ub.h = b;
  return __builtin_amdgcn_mfma_f32_16x16x16bf16_1k(ua.s, ub.s, c, 0, 0, 0);
#else
  (void)a; (void)b;
  return c;   // host stub, never executed
#endif
}

__device__ __forceinline__ float fast_exp2(float x) {
#if __has_builtin(__builtin_amdgcn_exp2f)
  return __builtin_amdgcn_exp2f(x);
#else
  return __expf(x * 0.6931471805599453f);
#endif
}

// ---------------------------------------------------------------------------
// GEMM: C[m][n] = sum_k A[m][k] * W[n][k] + bias[n]   (B^T layout)
// M=4096, N=1024, K=1024. 128x128 tile, BK=32, 4 waves (2x2 of 64x64),
// 16x16x32 bf16 MFMA, global_load_lds staging, 2-barrier loop (measured
// plateau; R10/R11 pipelining variants were null/worse).
// AF32/BF32: operand held fp32 in global AND LDS; staged by DMA (no VALU),
// converted to bf16 at fragment read (overlaps MFMA issue).
// Grid MUST be (8, 32[, z]); XCD-affinity: HW XCD = flat%8 = blockIdx.x;
// XCD x owns row-panels [x*4, x*4+4) (A panels hit one XCD L2).
// vfuse: V-instance epilogue writes directly into the 3 per-branch
// vt layouts (vt_b[seg][h][d][kj'] with kj' pair-permuted) instead of C.
// pair-permute: nw(kj) = (t16>>1)*32 + (j16>>2)*8 + (t16&1)*4 + (j16&3),
// t16 = (kj>>4)&3, j16 = kj&15 (matches the old vtrans layout exactly).
// ---------------------------------------------------------------------------
template <typename OutT, bool AF32, bool BF32>
__device__ __forceinline__ void gemm_body(const void* __restrict__ Ap,
                                          const void* __restrict__ Wp,
                                          const float* __restrict__ bias,
                                          OutT* __restrict__ C,
                                          bf16* __restrict__ vt0,
                                          bf16* __restrict__ vt1,
                                          bf16* __restrict__ vt2,
                                          const bool vfuse)
{
  constexpr int K = 1024;
  constexpr int ABYTES = AF32 ? 128 * 32 * 4 : 128 * 32 * 2;
  constexpr int BBYTES = BF32 ? 128 * 32 * 4 : 128 * 32 * 2;
  __shared__ __align__(16) char lA[ABYTES];
  __shared__ __align__(16) char lB[BBYTES];

  const int tid  = threadIdx.x;
  const int lane = tid & 63;
  const int w    = tid >> 6;
  const int quad = lane >> 4;
  const int l16  = lane & 15;
  const int wr   = w >> 1, wc = w & 1;
  // XCD-affinity remap (bijective over 8x32): ly=x*4+(y>>3), lx=y&7
  const int ly = blockIdx.x * 4 + (blockIdx.y >> 3);
  const int lx = blockIdx.y & 7;
  const int row0 = ly * 128;
  const int col0 = lx * 128;

  f32x4 acc[4][4] = {};

  // staging pointers. fp32 tile: 1024 16B-chunks (8/row); bf16: 512 (4/row).
  const float* Af32p[4]; const bf16* Ab16p[2];
  const float* Bf32p[4]; const bf16* Bb16p[2];
  if constexpr (AF32) {
    const float* Af = (const float*)Ap;
#pragma unroll
    for (int i = 0; i < 4; i++) {
      const int c = tid + 256 * i;
      Af32p[i] = Af + (size_t)(row0 + (c >> 3)) * K + (c & 7) * 4;
    }
  } else {
    const bf16* Ab = (const bf16*)Ap;
    Ab16p[0] = Ab + (size_t)(row0 + (tid >> 2)) * K + (tid & 3) * 8;
    Ab16p[1] = Ab + (size_t)(row0 + ((tid + 256) >> 2)) * K + ((tid + 256) & 3) * 8;
  }
  if constexpr (BF32) {
    const float* Bf = (const float*)Wp;
#pragma unroll
    for (int i = 0; i < 4; i++) {
      const int c = tid + 256 * i;
      Bf32p[i] = Bf + (size_t)(col0 + (c >> 3)) * K + (c & 7) * 4;
    }
  } else {
    const bf16* Bb = (const bf16*)Wp;
    Bb16p[0] = Bb + (size_t)(col0 + (tid >> 2)) * K + (tid & 3) * 8;
    Bb16p[1] = Bb + (size_t)(col0 + ((tid + 256) >> 2)) * K + ((tid + 256) & 3) * 8;
  }

  for (int kt = 0; kt < K; kt += 32) {
    __syncthreads();
    if constexpr (AF32) {
#pragma unroll
      for (int i = 0; i < 4; i++)
        gload16v(Af32p[i] + kt, (float*)lA + (tid + 256 * i) * 4);
    } else {
      gload16v(Ab16p[0] + kt, (bf16*)lA + tid * 8);
      gload16v(Ab16p[1] + kt, (bf16*)lA + (tid + 256) * 8);
    }
    if constexpr (BF32) {
#pragma unroll
      for (int i = 0; i < 4; i++)
        gload16v(Bf32p[i] + kt, (float*)lB + (tid + 256 * i) * 4);
    } else {
      gload16v(Bb16p[0] + kt, (bf16*)lB + tid * 8);
      gload16v(Bb16p[1] + kt, (bf16*)lB + (tid + 256) * 8);
    }
    __syncthreads();

    bf16x8 af[4], bfrag[4];
    if constexpr (AF32) {
      const float* fA = (const float*)lA;
#pragma unroll
      for (int mi = 0; mi < 4; mi++) {
        const int r = wr * 64 + mi * 16 + l16;
        float4 x = *(const float4*)&fA[r * 32 + quad * 8];
        float4 y = *(const float4*)&fA[r * 32 + quad * 8 + 4];
        af[mi] = bf16x8{ (bf16)x.x, (bf16)x.y, (bf16)x.z, (bf16)x.w,
                         (bf16)y.x, (bf16)y.y, (bf16)y.z, (bf16)y.w };
      }
    } else {
      const bf16* hA = (const bf16*)lA;
#pragma unroll
      for (int mi = 0; mi < 4; mi++)
        af[mi] = *(const bf16x8*)&hA[(wr * 64 + mi * 16 + l16) * 32 + quad * 8];
    }
    if constexpr (BF32) {
      const float* fB = (const float*)lB;
#pragma unroll
      for (int ni = 0; ni < 4; ni++) {
        const int r = wc * 64 + ni * 16 + l16;
        float4 x = *(const float4*)&fB[r * 32 + quad * 8];
        float4 y = *(const float4*)&fB[r * 32 + quad * 8 + 4];
        bfrag[ni] = bf16x8{ (bf16)x.x, (bf16)x.y, (bf16)x.z, (bf16)x.w,
                            (bf16)y.x, (bf16)y.y, (bf16)y.z, (bf16)y.w };
      }
    } else {
      const bf16* hB = (const bf16*)lB;
#pragma unroll
      for (int ni = 0; ni < 4; ni++)
        bfrag[ni] = *(const bf16x8*)&hB[(wc * 64 + ni * 16 + l16) * 32 + quad * 8];
    }
#pragma unroll
    for (int mi = 0; mi < 4; mi++)
#pragma unroll
      for (int ni = 0; ni < 4; ni++)
        acc[mi][ni] = __builtin_amdgcn_mfma_f32_16x16x32_bf16(
            af[mi], bfrag[ni], acc[mi][ni], 0, 0, 0);
  }

  if (!vfuse) {
#pragma unroll
    for (int mi = 0; mi < 4; mi++) {
#pragma unroll
      for (int ni = 0; ni < 4; ni++) {
        const int gcol = col0 + wc * 64 + ni * 16 + l16;
        const float bv = bias[gcol];
#pragma unroll
        for (int r = 0; r < 4; r++) {
          const int grow = row0 + wr * 64 + mi * 16 + quad * 4 + r;
          C[(size_t)grow * 1024 + gcol] = (OutT)(acc[mi][ni][r] + bv);
        }
      }
    }
  } else {
    // V-instance: scatter biased C directly into vt0/vt1/vt2.
    const int h    = 2 * lx + wc;          // this wave's head (cols h*64..h*64+63)
    const int grp1 = h >> 3, grp2 = h >> 2;
#pragma unroll
    for (int mi = 0; mi < 4; mi++) {
      const int p0 = row0 + wr * 64 + mi * 16 + quad * 4;   // aligned 4
      // branch 0 (dr=1, sl=1024): kj = pos0 + r
      const int seg0 = p0 >> 10;
      const int pos0 = p0 & 1023;
      const int nw0  = ((pos0 >> 5) & 1) * 32 + ((pos0 >> 2) & 3) * 8
                     + ((pos0 >> 4) & 1) * 4;                // (pos0&3)==0
      const int kt0  = (pos0 >> 6) * 64;
      // branch 1 (dr=2, sl=2048): kept r in {grp1, grp1+2}; kj = kja, kja+1
      const int seg1 = p0 >> 11;
      const int kja  = (p0 & 2047) >> 1;                     // aligned 2
      const int nw1  = ((kja >> 5) & 1) * 32 + ((kja >> 2) & 3) * 8
                     + ((kja >> 4) & 1) * 4 + (kja & 3);     // even
      const int kt1  = (kja >> 6) * 64;
      // branch 2 (dr=4, sl=4096): kept r = grp2; kj2 = p0>>2
      const int kj2  = p0 >> 2;
      const int nw2  = ((kj2 >> 5) & 1) * 32 + ((kj2 >> 2) & 3) * 8
                     + ((kj2 >> 4) & 1) * 4 + (kj2 & 3);
      const int kt2  = (kj2 >> 6) * 64;
#pragma unroll
      for (int ni = 0; ni < 4; ni++) {
        const int d  = ni * 16 + l16;
        const float bv = bias[col0 + wc * 64 + d];
        const float v0 = acc[mi][ni][0] + bv;
        const float v1 = acc[mi][ni][1] + bv;
        const float v2 = acc[mi][ni][2] + bv;
        const float v3 = acc[mi][ni][3] + bv;
        {
          bf16x4 o = { (bf16)v0, (bf16)v1, (bf16)v2, (bf16)v3 };
          *(bf16x4*)(vt0 + (size_t)((seg0 * 16 + h) * 64 + d) * 1024 + kt0 + nw0) = o;
        }
        {
          const float a = grp1 ? v1 : v0;    // r = grp1
          const float b = grp1 ? v3 : v2;    // r = grp1 + 2
          bf16x2 o = { (bf16)a, (bf16)b };
          *(bf16x2*)(vt1 + (size_t)((seg1 * 16 + h) * 64 + d) * 1024 + kt1 + nw1) = o;
        }
        {
          const float a = (grp2 == 0) ? v0 : (grp2 == 1) ? v1
                         : (grp2 == 2) ? v2 : v3;            // r = grp2
          vt2[(size_t)(h * 64 + d) * 1024 + kt2 + nw2] = (bf16)a;
        }
      }
    }
  }
}

__global__ __launch_bounds__(256) void gemm_qkv_kernel(
    const float* q, const float* k, const float* v,
    const float* wq, const float* wk, const float* wv,
    const float* bq, const float* bk, const float* bv,
    bf16* qo, bf16* ko,
    bf16* vt0, bf16* vt1, bf16* vt2)
{
  if (blockIdx.z == 0)
    gemm_body<bf16, true, true>(q, wq, bq, qo, nullptr, nullptr, nullptr, false);
  else if (blockIdx.z == 1)
    gemm_body<bf16, true, true>(k, wk, bk, ko, nullptr, nullptr, nullptr, false);
  else
    gemm_body<bf16, true, true>(v, wv, bv, (bf16*)nullptr, vt0, vt1, vt2, true);
}

__global__ __launch_bounds__(256) void gemm_out_kernel(
    const bf16* A, const float* W, const float* bias, float* C)
{
  gemm_body<float, false, true>(A, W, bias, C, nullptr, nullptr, nullptr, false);
}

// ---------------------------------------------------------------------------
// Flash attention, transposed-S form with XOR-swizzled LDS tiles.
// Block = (branch, seg, h, pair j): q-tiles qtA = 15-j and qtB = j over one
// shared staged K/V stream. Dual-tile fused compute: both tiles consume the
// SAME K/V fragments, softmax chains interleave. l-sum via ones-MFMA.
// ---------------------------------------------------------------------------
__global__ __launch_bounds__(256, 4) void attn_kernel(
    const bf16* __restrict__ qg, const bf16* __restrict__ kg,
    const bf16* vt0, const bf16* vt1, const bf16* vt2,
    bf16* o0, bf16* o1, bf16* o2,
    float* l0, float* l1, float* l2)
{
  __shared__ __align__(16) bf16 lK[2][64 * 64];     // [kj][d], swizzled
  __shared__ __align__(16) bf16 lV[2][64 * 64];     // [d][kj'], swizzled

  // XCD-affinity remap (bijective, 896 = 8*112): hardware assigns block b to
  // XCD b%8; logical id o = (b&7)*112 + (b>>3) gives each XCD a contiguous
  // run of 112 logical blocks = 14 (seg,h) groups -> K/V fits that XCD's L2.
  const int bid0 = blockIdx.x;
  const int o = (bid0 & 7) * 112 + (bid0 >> 3);

  int sl, dr, rem, shift;
  const bf16* vt; bf16* ob; float* lseb;
  if (o < 512)      { sl = 1024; dr = 1; rem = o;       vt = vt0; ob = o0; lseb = l0; shift = 4; }
  else if (o < 768) { sl = 2048; dr = 2; rem = o - 512; vt = vt1; ob = o1; lseb = l1; shift = 3; }
  else              { sl = 4096; dr = 4; rem = o - 768; vt = vt2; ob = o2; lseb = l2; shift = 2; }
  const int j   = rem & 7;
  const int h   = (rem >> 3) & 15;
  const int seg = rem >> 7;
  const int qtA = 15 - j;                // high q-tile (16-j k-iterations)
  const int qtB = j;                     // low q-tile  (j+1 k-iterations); qtB < qtA
  const int grp = h >> shift;
  const int segbase = seg * sl;

  const int tid = threadIdx.x, lane = tid & 63, w = tid >> 6;
  const int quad = lane >> 4, l16 = lane & 15;
  const int rs8 = l16 & 7;               // row-XOR term: (kj&7)==(drow&7)==l16&7

  // Q fragments (B-operand of S^T MFMA): B[k=d=quad*8+j][n=q=l16]
  auto loadq = [&](int qt, bf16x8& a0, bf16x8& a1) {
    const int qi = qt * 64 + w * 16 + l16;
    const size_t p = (size_t)(segbase + qi * dr + grp);
    const bf16* qp = qg + p * EDIM + h * 64 + quad * 8;
    a0 = *(const bf16x8*)(qp);
    a1 = *(const bf16x8*)(qp + 32);
  };
  bf16x8 qaA0, qaA1, qaB0, qaB1;
  loadq(qtA, qaA0, qaA1);
  loadq(qtB, qaB0, qaB1);

  f32x4 OA[4] = {}, OB[4] = {};          // O^T frags: col l16=q, row = d
  f32x4 lsA = {0.f, 0.f, 0.f, 0.f};      // l accumulated by ones-MFMA
  f32x4 lsB = {0.f, 0.f, 0.f, 0.f};
  float mA = -__builtin_inff();          // m in log2 units
  float mB = -__builtin_inff();
  const bf16x4 ONES = { (bf16)1.f, (bf16)1.f, (bf16)1.f, (bf16)1.f };

  const bf16* vbase = vt + (size_t)(seg * NH + h) * 64 * GLEN;
  const int c0 = tid, c1 = tid + 256;
  // staging-source permutation implementing the XOR swizzle:
  // LDS chunk position p (=c0/c1) is row r=p>>3, slot s=p&7; it must receive
  // global chunk c = s ^ (r & 7).
  const int r0 = c0 >> 3, sw0 = ((c0 & 7) ^ (r0 & 7));
  const int r1 = c1 >> 3, sw1 = ((c1 & 7) ^ (r1 & 7));

  // incremental staging pointers (advance one k-tile per stage call)
  const bf16* kp0 = kg + (size_t)(segbase + r0 * dr + grp) * EDIM + h * 64 + sw0 * 8;
  const bf16* kp1 = kg + (size_t)(segbase + r1 * dr + grp) * EDIM + h * 64 + sw1 * 8;
  const bf16* vp0 = vbase + (size_t)r0 * GLEN + sw0 * 8;
  const bf16* vp1 = vbase + (size_t)r1 * GLEN + sw1 * 8;
  const size_t kstep = (size_t)64 * dr * EDIM;

  auto stage = [&](int buf) {
    gload16(kp0, &lK[buf][c0 * 8]);
    gload16(kp1, &lK[buf][c1 * 8]);
    gload16(vp0, &lV[buf][c0 * 8]);
    gload16(vp1, &lV[buf][c1 * 8]);
    kp0 += kstep; kp1 += kstep; vp0 += 64; vp1 += 64;
  };

  const float CS = 0.18033688011112042f;   // (1/sqrt(64)) * log2(e)
  const float NEGINF = -__builtin_inff();
  const int qiA = qtA * 64 + w * 16 + l16;
  const int qiB = qtB * 64 + w * 16 + l16;

  // loop-invariant LDS read bases (K: kj = t*16+l16 -> +t*1024; V: +nf*1024)
  const int kb0 = l16 * 64 + ((quad ^ rs8) * 8);
  const int kb1 = l16 * 64 + (((4 + quad) ^ rs8) * 8);
  const int vb0 = l16 * 64;

  // Fused dual-tile compute. HAS_B: tile B active this k-tile. DIAG_A/B:
  // causal-diagonal masking for that tile (DIAG_A implies !HAS_B).
  auto comp = [&](auto hasB_, auto diagA_, auto diagB_, int kt) {
    constexpr bool HAS_B  = decltype(hasB_)::v;
    constexpr bool DIAG_A = decltype(diagA_)::v;
    constexpr bool DIAG_B = decltype(diagB_)::v;
    const bf16* bK = lK[kt & 1];
    const bf16* bV = lV[kt & 1];

    // --- S^T = K Q^T for both tiles off shared K fragments ---
    f32x4 sA[4], sB[4];
#pragma unroll
    for (int t = 0; t < 4; t++) {
      const bool aA = !DIAG_A || t <= w;
      const bool aB = HAS_B && (!DIAG_B || t <= w);
      if (aA || aB) {
        bf16x8 ka0 = *(const bf16x8*)&bK[kb0 + t * 1024];
        bf16x8 ka1 = *(const bf16x8*)&bK[kb1 + t * 1024];
        if (aA) {
          sA[t] = f32x4{0.f, 0.f, 0.f, 0.f};
          sA[t] = __builtin_amdgcn_mfma_f32_16x16x32_bf16(ka0, qaA0, sA[t], 0, 0, 0);
          sA[t] = __builtin_amdgcn_mfma_f32_16x16x32_bf16(ka1, qaA1, sA[t], 0, 0, 0);
        }
        if (aB) {
          sB[t] = f32x4{0.f, 0.f, 0.f, 0.f};
          sB[t] = __builtin_amdgcn_mfma_f32_16x16x32_bf16(ka0, qaB0, sB[t], 0, 0, 0);
          sB[t] = __builtin_amdgcn_mfma_f32_16x16x32_bf16(ka1, qaB1, sB[t], 0, 0, 0);
        }
      }
    }

    // --- masked raw max, vector partials ---
    f32x4 mvA = {NEGINF, NEGINF, NEGINF, NEGINF};
    f32x4 mvB = {NEGINF, NEGINF, NEGINF, NEGINF};
#pragma unroll
    for (int t = 0; t < 4; t++) {
      if (!DIAG_A || t <= w) {
#pragma unroll
        for (int r = 0; r < 4; r++) {
          float sv = sA[t][r];
          if (DIAG_A) {
            const int kj = kt * 64 + t * 16 + quad * 4 + r;
            if (kj > qiA) sv = NEGINF;
          }
          sA[t][r] = sv;
          mvA[r] = fmaxf(mvA[r], sv);
        }
      }
      if (HAS_B && (!DIAG_B || t <= w)) {
#pragma unroll
        for (int r = 0; r < 4; r++) {
          float sv = sB[t][r];
          if (DIAG_B) {
            const int kj = kt * 64 + t * 16 + quad * 4 + r;
            if (kj > qiB) sv = NEGINF;
          }
          sB[t][r] = sv;
          mvB[r] = fmaxf(mvB[r], sv);
        }
      }
    }
    float mrA = fmaxf(fmaxf(mvA[0], mvA[1]), fmaxf(mvA[2], mvA[3]));
    float mrB = fmaxf(fmaxf(mvB[0], mvB[1]), fmaxf(mvB[2], mvB[3]));
    mrA = fmaxf(mrA, __shfl_xor(mrA, 16, 64));
    mrA = fmaxf(mrA, __shfl_xor(mrA, 32, 64));
    if constexpr (HAS_B) {
      mrB = fmaxf(mrB, __shfl_xor(mrB, 16, 64));
      mrB = fmaxf(mrB, __shfl_xor(mrB, 32, 64));
    }

    // --- defer-rescale (T13), wave-uniform skip ---
    {
      const float mnew = fmaxf(mA, mrA * CS);
      if (!__all(mnew - mA <= 8.0f)) {
        const float alpha = fast_exp2(mA - mnew);   // first tile: exp2(-inf)=0
#pragma unroll
        for (int nf = 0; nf < 4; nf++)
#pragma unroll
          for (int r = 0; r < 4; r++) OA[nf][r] *= alpha;
#pragma unroll
        for (int r = 0; r < 4; r++) lsA[r] *= alpha;
        mA = mnew;
      }
    }
    if constexpr (HAS_B) {
      const float mnew = fmaxf(mB, mrB * CS);
      if (!__all(mnew - mB <= 8.0f)) {
        const float alpha = fast_exp2(mB - mnew);
#pragma unroll
        for (int nf = 0; nf < 4; nf++)
#pragma unroll
          for (int r = 0; r < 4; r++) OB[nf][r] *= alpha;
#pragma unroll
        for (int r = 0; r < 4; r++) lsB[r] *= alpha;
        mB = mnew;
      }
    }

    // --- p = exp2(fma(s_raw, CS, -m)) <= 2^8; bf16 pack ---
    bf16x4 pbA[4], pbB[4];
#pragma unroll
    for (int t = 0; t < 4; t++) {
      if (!DIAG_A || t <= w) {
#pragma unroll
        for (int r = 0; r < 4; r++)
          pbA[t][r] = (bf16)fast_exp2(__builtin_fmaf(sA[t][r], CS, -mA));
      }
      if (HAS_B && (!DIAG_B || t <= w)) {
#pragma unroll
        for (int r = 0; r < 4; r++)
          pbB[t][r] = (bf16)fast_exp2(__builtin_fmaf(sB[t][r], CS, -mB));
      }
    }

    // --- O^T += V^T P^T off shared V fragments (paired b128 reads);
    //     l += ones-MFMA(P^T): full 64-kpos row sum incl. cross-quad ---
#pragma unroll
    for (int p2 = 0; p2 < 2; p2++) {
      const int t0 = 2 * p2, t1 = t0 + 1;
      const bool aA0 = !DIAG_A || t0 <= w;
      const bool aA1 = !DIAG_A || t1 <= w;
      const bool aB0 = HAS_B && (!DIAG_B || t0 <= w);
      const bool aB1 = HAS_B && (!DIAG_B || t1 <= w);
      if (aA0 || aA1 || aB0 || aB1) {
        const int cx = ((p2 * 4 + quad) ^ rs8) * 8;
#pragma unroll
        for (int nf = 0; nf < 4; nf++) {
          bf16x8 va8 = *(const bf16x8*)&bV[vb0 + nf * 1024 + cx];
          bf16x4 vlo = __builtin_shufflevector(va8, va8, 0, 1, 2, 3);
          bf16x4 vhi = __builtin_shufflevector(va8, va8, 4, 5, 6, 7);
          if (aA0) OA[nf] = mfma16x16x16_bf16(vlo, pbA[t0], OA[nf]);
          if (aA1) OA[nf] = mfma16x16x16_bf16(vhi, pbA[t1], OA[nf]);
          if (aB0) OB[nf] = mfma16x16x16_bf16(vlo, pbB[t0], OB[nf]);
          if (aB1) OB[nf] = mfma16x16x16_bf16(vhi, pbB[t1], OB[nf]);
        }
        if (aA0) lsA = mfma16x16x16_bf16(ONES, pbA[t0], lsA);
        if (aA1) lsA = mfma16x16x16_bf16(ONES, pbA[t1], lsA);
        if (aB0) lsB = mfma16x16x16_bf16(ONES, pbB[t0], lsB);
        if (aB1) lsB = mfma16x16x16_bf16(ONES, pbB[t1], lsB);
      }
    }
  };

  stage(0);
  int kt = 0;
  // Phase 1: both tiles, no diagonal (kt < qtB)
  for (; kt < qtB; kt++) {
    __syncthreads();
    stage((kt + 1) & 1);
    comp(Flag<true>{}, Flag<false>{}, Flag<false>{}, kt);
  }
  // kt == qtB: tile A full, tile B diagonal (qtB < qtA always)
  __syncthreads();
  stage((kt + 1) & 1);
  comp(Flag<true>{}, Flag<false>{}, Flag<true>{}, kt);
  kt++;
  // Phase 2: tile A only (qtB < kt < qtA)
  for (; kt < qtA; kt++) {
    __syncthreads();
    stage((kt + 1) & 1);
    comp(Flag<false>{}, Flag<false>{}, Flag<false>{}, kt);
  }
  // kt == qtA: tile A diagonal
  __syncthreads();
  comp(Flag<false>{}, Flag<true>{}, Flag<false>{}, kt);

  // epilogue: lane l16 owns q column; d = nf*16 + quad*4 + r (4 contiguous)
  auto epilogue = [&](const f32x4 (&Oa)[4], float m_r, float l_r, int qt) {
    const int qi = qt * 64 + w * 16 + l16;
    const float linv = 1.0f / l_r;
    const int pdense = segbase + qi * dr + grp;
    bf16* orow = ob + (size_t)pdense * EDIM + h * 64;
#pragma unroll
    for (int nf = 0; nf < 4; nf++) {
      bf16x4 ov;
#pragma unroll
      for (int r = 0; r < 4; r++) ov[r] = (bf16)(Oa[nf][r] * linv);
      *(bf16x4*)(orow + nf * 16 + quad * 4) = ov;
    }
    if (quad == 0)
      lseb[h * L_SEQ + pdense] = m_r * 0.6931471805599453f + __logf(l_r);
  };
  epilogue(OA, mA, lsA[0], qtA);
  epilogue(OB, mB, lsB[0], qtB);
}

// ---------------------------------------------------------------------------
// Merge: softmax over branch lse at each (h,p); coverage computed analytically.
// ---------------------------------------------------------------------------
__global__ __launch_bounds__(256) void merge_kernel(
    const bf16* __restrict__ o0, const bf16* __restrict__ o1, const bf16* __restrict__ o2,
    const float* __restrict__ l0, const float* __restrict__ l1, const float* __restrict__ l2,
    bf16* __restrict__ merged)
{
  const int idx = blockIdx.x * 256 + threadIdx.x;   // over L*H*8
  const int dc = idx & 7;
  const int h  = (idx >> 3) & 15;
  const int p  = idx >> 7;
  const bool c1 = ((p & 1) == (h >> 3));   // branch dr=2 coverage
  const bool c2 = ((p & 3) == (h >> 2));   // branch dr=4 coverage
  const float s0 = l0[h * L_SEQ + p];
  const float s1 = c1 ? l1[h * L_SEQ + p] : -__builtin_inff();
  const float s2 = c2 ? l2[h * L_SEQ + p] : -__builtin_inff();
  const float mx = fmaxf(s0, fmaxf(s1, s2));
  float w0 = __expf(s0 - mx);
  float w1 = c1 ? __expf(s1 - mx) : 0.f;
  float w2 = c2 ? __expf(s2 - mx) : 0.f;
  const float inv = 1.0f / (w0 + w1 + w2);
  w0 *= inv; w1 *= inv; w2 *= inv;

  const size_t off = (size_t)p * EDIM + h * 64 + dc * 8;
  float acc[8];
  bf16x8 a0 = *(const bf16x8*)(o0 + off);
#pragma unroll
  for (int j = 0; j < 8; j++) acc[j] = w0 * (float)a0[j];
  if (c1) {
    bf16x8 a1 = *(const bf16x8*)(o1 + off);
#pragma unroll
    for (int j = 0; j < 8; j++) acc[j] += w1 * (float)a1[j];
  }
  if (c2) {
    bf16x8 a2 = *(const bf16x8*)(o2 + off);
#pragma unroll
    for (int j = 0; j < 8; j++) acc[j] += w2 * (float)a2[j];
  }
  bf16x8 r;
#pragma unroll
  for (int j = 0; j < 8; j++) r[j] = (bf16)acc[j];
  *(bf16x8*)(merged + off) = r;
}

// ---------------------------------------------------------------------------
extern "C" void kernel_launch(void* const* d_in, const int* in_sizes, int n_in,
                              void* d_out, int out_size, void* d_ws, size_t ws_size,
                              hipStream_t stream)
{
  (void)in_sizes; (void)n_in; (void)out_size; (void)ws_size;
  const float* query = (const float*)d_in[0];
  const float* key   = (const float*)d_in[1];
  const float* value = (const float*)d_in[2];
  const float* Wq = (const float*)d_in[3];
  const float* bq = (const float*)d_in[4];
  const float* Wk = (const float*)d_in[5];
  const float* bk = (const float*)d_in[6];
  const float* Wv = (const float*)d_in[7];
  const float* bv = (const float*)d_in[8];
  const float* Wo = (const float*)d_in[9];
  const float* bo = (const float*)d_in[10];

  char* base = (char*)d_ws;
  size_t off = 0;
  auto take = [&](size_t nbytes) -> char* {
    char* p = base + off;
    off += (nbytes + 255) & ~(size_t)255;
    return p;
  };
  const size_t LE2 = (size_t)L_SEQ * EDIM * 2;
  bf16* qb  = (bf16*)take(LE2);
  bf16* kb  = (bf16*)take(LE2);
  bf16* o0  = (bf16*)take(LE2);
  bf16* o1  = (bf16*)take(LE2);
  bf16* o2  = (bf16*)take(LE2);
  bf16* vt0 = (bf16*)take((size_t)4 * NH * HD * GLEN * 2);
  bf16* vt1 = (bf16*)take((size_t)2 * NH * HD * GLEN * 2);
  bf16* vt2 = (bf16*)take((size_t)1 * NH * HD * GLEN * 2);
  float* lse0 = (float*)take((size_t)NH * L_SEQ * 4);
  float* lse1 = (float*)take((size_t)NH * L_SEQ * 4);
  float* lse2 = (float*)take((size_t)NH * L_SEQ * 4);
  bf16* merged = (bf16*)take(LE2);

  dim3 blk(256);
  gemm_qkv_kernel<<<dim3(8, 32, 3), blk, 0, stream>>>(
      query, key, value, Wq, Wk, Wv, bq, bk, bv, qb, kb, vt0, vt1, vt2);
  attn_kernel<<<dim3(896), blk, 0, stream>>>(
      qb, kb, vt0, vt1, vt2, o0, o1, o2, lse0, lse1, lse2);
  merge_kernel<<<dim3(2048), blk, 0, stream>>>(
      o0, o1, o2, lse0, lse1, lse2, merged);
  gemm_out_kernel<<<dim3(8, 32), blk, 0, stream>>>(merged, Wo, bo, (float*)d_out);
}

// Round 10
// 246.098 us; speedup vs baseline: 2.0596x; 2.0596x over previous
//
#include <hip/hip_runtime.h>
#include <math.h>

// DilatedAttention on MI355X (gfx950), bf16 MFMA implementation.
// L=4096, E=1024, H=16, D=64. Branches (sl,dr) = (1024,1),(2048,2),(4096,4).
// Every branch reduces to causal attention over g=1024 sparse positions.
//
// Attention in transposed-S form:
//   S^T = K Q^T  (lane l16 = q column)
//   O^T = V^T P^T with 16x16x16 MFMA    -> P^T registers are the B-operand.
// R4: XOR-swizzled attn LDS tiles via staging-source permutation.
// R5: q-tile PAIR (j, 15-j) per block: exactly 17 tile-computes each.
// R6: fused dual-tile compute (shared K/V fragments, interleaved chains).
// R7: GEMM/attn XCD-affinity remaps; V^T pair-permuted (bank conflicts -> 0).
// R8: attn l-sum via ones-MFMA; setprio removed (measured regression).
// R9-R11 (FAILED/NULL): reg-staged cvt fusion; T3/T4 pipelining on 128² GEMM.
// R12 (WIN, -10us): vtrans fused into gemm_qkv V epilogue (6 -> 5 launches).
// R13 (REGRESSED 302us): fp32 GEMM operands -- fp32 LDS tile has 128B rows,
// fragment read = 16 lanes x same chunk column x 16 rows = 16-way bank
// conflict (SQ_LDS_BANK_CONFLICT 3.1M -> 1.37e8). Guide G4's exact case.
// R14: keep R13's structure (cvt deleted, 4 launches, DMA staging, cvt at
// fragment read) + fix the conflict with the attn-validated XOR swizzle
// (rule #21): LDS dest stays linear, staging SOURCE pre-swizzled
// (chunk slot s receives global chunk s ^ (row&7)), fragment READ applies
// the same XOR -- 16 lanes spread over 8 chunk slots = 2 lanes/bank = free.

#define L_SEQ 4096
#define EDIM  1024
#define NH    16
#define HD    64
#define GLEN  1024

typedef __bf16 bf16;
typedef __bf16 bf16x8 __attribute__((ext_vector_type(8)));
typedef __bf16 bf16x4 __attribute__((ext_vector_type(4)));
typedef __bf16 bf16x2 __attribute__((ext_vector_type(2)));
typedef short  s16x4  __attribute__((ext_vector_type(4)));
typedef float  f32x4  __attribute__((ext_vector_type(4)));

template <bool B> struct Flag { static constexpr bool v = B; };

// async global->LDS, 16B per lane. LDS dest semantics: wave-uniform base + lane*16.
__device__ __forceinline__ void gload16v(const void* g, void* l) {
  __builtin_amdgcn_global_load_lds(
      (__attribute__((address_space(1))) void*)(const_cast<void*>(g)),
      (__attribute__((address_space(3))) void*)(l),
      16, 0, 0);
}
__device__ __forceinline__ void gload16(const bf16* g, bf16* l) {
  gload16v((const void*)g, (void*)l);
}

// v_mfma_f32_16x16x16_bf16 (builtin name only exists in the device pass).
__device__ __forceinline__ f32x4 mfma16x16x16_bf16(bf16x4 a, bf16x4 b, f32x4 c) {
#if defined(__HIP_DEVICE_COMPILE__)
  union { bf16x4 h; s16x4 s; } ua, ub;
  ua.h = a; ub.h = b;
  return __builtin_amdgcn_mfma_f32_16x16x16bf16_1k(ua.s, ub.s, c, 0, 0, 0);
#else
  (void)a; (void)b;
  return c;   // host stub, never executed
#endif
}

__device__ __forceinline__ float fast_exp2(float x) {
#if __has_builtin(__builtin_amdgcn_exp2f)
  return __builtin_amdgcn_exp2f(x);
#else
  return __expf(x * 0.6931471805599453f);
#endif
}

// ---------------------------------------------------------------------------
// GEMM: C[m][n] = sum_k A[m][k] * W[n][k] + bias[n]   (B^T layout)
// M=4096, N=1024, K=1024. 128x128 tile, BK=32, 4 waves (2x2 of 64x64),
// 16x16x32 bf16 MFMA, global_load_lds staging, 2-barrier loop (measured
// plateau; R10/R11 pipelining variants were null/worse).
// AF32/BF32: operand fp32 in global AND LDS; staged by DMA with the
// SOURCE-side XOR swizzle (chunk slot s of row r receives global chunk
// s ^ (r&7)); fragment read applies the same XOR -> conflict-free.
// fp32->bf16 conversion happens at fragment read (overlaps MFMA issue).
// Grid MUST be (8, 32[, z]); XCD-affinity: HW XCD = flat%8 = blockIdx.x;
// XCD x owns row-panels [x*4, x*4+4) (A panels hit one XCD L2).
// vfuse: V-instance epilogue writes directly into the 3 per-branch
// vt layouts (vt_b[seg][h][d][kj'] with kj' pair-permuted) instead of C.
// pair-permute: nw(kj) = (t16>>1)*32 + (j16>>2)*8 + (t16&1)*4 + (j16&3),
// t16 = (kj>>4)&3, j16 = kj&15 (matches the old vtrans layout exactly).
// ---------------------------------------------------------------------------
template <typename OutT, bool AF32, bool BF32>
__device__ __forceinline__ void gemm_body(const void* __restrict__ Ap,
                                          const void* __restrict__ Wp,
                                          const float* __restrict__ bias,
                                          OutT* __restrict__ C,
                                          bf16* __restrict__ vt0,
                                          bf16* __restrict__ vt1,
                                          bf16* __restrict__ vt2,
                                          const bool vfuse)
{
  constexpr int K = 1024;
  constexpr int ABYTES = AF32 ? 128 * 32 * 4 : 128 * 32 * 2;
  constexpr int BBYTES = BF32 ? 128 * 32 * 4 : 128 * 32 * 2;
  __shared__ __align__(16) char lA[ABYTES];
  __shared__ __align__(16) char lB[BBYTES];

  const int tid  = threadIdx.x;
  const int lane = tid & 63;
  const int w    = tid >> 6;
  const int quad = lane >> 4;
  const int l16  = lane & 15;
  const int wr   = w >> 1, wc = w & 1;
  // XCD-affinity remap (bijective over 8x32): ly=x*4+(y>>3), lx=y&7
  const int ly = blockIdx.x * 4 + (blockIdx.y >> 3);
  const int lx = blockIdx.y & 7;
  const int row0 = ly * 128;
  const int col0 = lx * 128;

  f32x4 acc[4][4] = {};

  // staging pointers. fp32 tile: 1024 16B-chunks (8/row, SOURCE-swizzled);
  // bf16 tile: 512 chunks (4/row, linear -- conflicts measured mild).
  const float* Af32p[4]; const bf16* Ab16p[2];
  const float* Bf32p[4]; const bf16* Bb16p[2];
  if constexpr (AF32) {
    const float* Af = (const float*)Ap;
#pragma unroll
    for (int i = 0; i < 4; i++) {
      const int c = tid + 256 * i;
      const int rp = c >> 3, sp = c & 7;
      Af32p[i] = Af + (size_t)(row0 + rp) * K + (sp ^ (rp & 7)) * 4;
    }
  } else {
    const bf16* Ab = (const bf16*)Ap;
    Ab16p[0] = Ab + (size_t)(row0 + (tid >> 2)) * K + (tid & 3) * 8;
    Ab16p[1] = Ab + (size_t)(row0 + ((tid + 256) >> 2)) * K + ((tid + 256) & 3) * 8;
  }
  if constexpr (BF32) {
    const float* Bf = (const float*)Wp;
#pragma unroll
    for (int i = 0; i < 4; i++) {
      const int c = tid + 256 * i;
      const int rp = c >> 3, sp = c & 7;
      Bf32p[i] = Bf + (size_t)(col0 + rp) * K + (sp ^ (rp & 7)) * 4;
    }
  } else {
    const bf16* Bb = (const bf16*)Wp;
    Bb16p[0] = Bb + (size_t)(col0 + (tid >> 2)) * K + (tid & 3) * 8;
    Bb16p[1] = Bb + (size_t)(col0 + ((tid + 256) >> 2)) * K + ((tid + 256) & 3) * 8;
  }

  for (int kt = 0; kt < K; kt += 32) {
    __syncthreads();
    if constexpr (AF32) {
#pragma unroll
      for (int i = 0; i < 4; i++)
        gload16v(Af32p[i] + kt, (float*)lA + (tid + 256 * i) * 4);
    } else {
      gload16v(Ab16p[0] + kt, (bf16*)lA + tid * 8);
      gload16v(Ab16p[1] + kt, (bf16*)lA + (tid + 256) * 8);
    }
    if constexpr (BF32) {
#pragma unroll
      for (int i = 0; i < 4; i++)
        gload16v(Bf32p[i] + kt, (float*)lB + (tid + 256 * i) * 4);
    } else {
      gload16v(Bb16p[0] + kt, (bf16*)lB + tid * 8);
      gload16v(Bb16p[1] + kt, (bf16*)lB + (tid + 256) * 8);
    }
    __syncthreads();

    bf16x8 af[4], bfrag[4];
    if constexpr (AF32) {
      const float* fA = (const float*)lA;
#pragma unroll
      for (int mi = 0; mi < 4; mi++) {
        const int r = wr * 64 + mi * 16 + l16;
        const int rs = r & 7;
        float4 x = *(const float4*)&fA[r * 32 + (((2 * quad)     ^ rs) * 4)];
        float4 y = *(const float4*)&fA[r * 32 + (((2 * quad + 1) ^ rs) * 4)];
        af[mi] = bf16x8{ (bf16)x.x, (bf16)x.y, (bf16)x.z, (bf16)x.w,
                         (bf16)y.x, (bf16)y.y, (bf16)y.z, (bf16)y.w };
      }
    } else {
      const bf16* hA = (const bf16*)lA;
#pragma unroll
      for (int mi = 0; mi < 4; mi++)
        af[mi] = *(const bf16x8*)&hA[(wr * 64 + mi * 16 + l16) * 32 + quad * 8];
    }
    if constexpr (BF32) {
      const float* fB = (const float*)lB;
#pragma unroll
      for (int ni = 0; ni < 4; ni++) {
        const int r = wc * 64 + ni * 16 + l16;
        const int rs = r & 7;
        float4 x = *(const float4*)&fB[r * 32 + (((2 * quad)     ^ rs) * 4)];
        float4 y = *(const float4*)&fB[r * 32 + (((2 * quad + 1) ^ rs) * 4)];
        bfrag[ni] = bf16x8{ (bf16)x.x, (bf16)x.y, (bf16)x.z, (bf16)x.w,
                            (bf16)y.x, (bf16)y.y, (bf16)y.z, (bf16)y.w };
      }
    } else {
      const bf16* hB = (const bf16*)lB;
#pragma unroll
      for (int ni = 0; ni < 4; ni++)
        bfrag[ni] = *(const bf16x8*)&hB[(wc * 64 + ni * 16 + l16) * 32 + quad * 8];
    }
#pragma unroll
    for (int mi = 0; mi < 4; mi++)
#pragma unroll
      for (int ni = 0; ni < 4; ni++)
        acc[mi][ni] = __builtin_amdgcn_mfma_f32_16x16x32_bf16(
            af[mi], bfrag[ni], acc[mi][ni], 0, 0, 0);
  }

  if (!vfuse) {
#pragma unroll
    for (int mi = 0; mi < 4; mi++) {
#pragma unroll
      for (int ni = 0; ni < 4; ni++) {
        const int gcol = col0 + wc * 64 + ni * 16 + l16;
        const float bv = bias[gcol];
#pragma unroll
        for (int r = 0; r < 4; r++) {
          const int grow = row0 + wr * 64 + mi * 16 + quad * 4 + r;
          C[(size_t)grow * 1024 + gcol] = (OutT)(acc[mi][ni][r] + bv);
        }
      }
    }
  } else {
    // V-instance: scatter biased C directly into vt0/vt1/vt2.
    const int h    = 2 * lx + wc;          // this wave's head (cols h*64..h*64+63)
    const int grp1 = h >> 3, grp2 = h >> 2;
#pragma unroll
    for (int mi = 0; mi < 4; mi++) {
      const int p0 = row0 + wr * 64 + mi * 16 + quad * 4;   // aligned 4
      // branch 0 (dr=1, sl=1024): kj = pos0 + r
      const int seg0 = p0 >> 10;
      const int pos0 = p0 & 1023;
      const int nw0  = ((pos0 >> 5) & 1) * 32 + ((pos0 >> 2) & 3) * 8
                     + ((pos0 >> 4) & 1) * 4;                // (pos0&3)==0
      const int kt0  = (pos0 >> 6) * 64;
      // branch 1 (dr=2, sl=2048): kept r in {grp1, grp1+2}; kj = kja, kja+1
      const int seg1 = p0 >> 11;
      const int kja  = (p0 & 2047) >> 1;                     // aligned 2
      const int nw1  = ((kja >> 5) & 1) * 32 + ((kja >> 2) & 3) * 8
                     + ((kja >> 4) & 1) * 4 + (kja & 3);     // even
      const int kt1  = (kja >> 6) * 64;
      // branch 2 (dr=4, sl=4096): kept r = grp2; kj2 = p0>>2
      const int kj2  = p0 >> 2;
      const int nw2  = ((kj2 >> 5) & 1) * 32 + ((kj2 >> 2) & 3) * 8
                     + ((kj2 >> 4) & 1) * 4 + (kj2 & 3);
      const int kt2  = (kj2 >> 6) * 64;
#pragma unroll
      for (int ni = 0; ni < 4; ni++) {
        const int d  = ni * 16 + l16;
        const float bv = bias[col0 + wc * 64 + d];
        const float v0 = acc[mi][ni][0] + bv;
        const float v1 = acc[mi][ni][1] + bv;
        const float v2 = acc[mi][ni][2] + bv;
        const float v3 = acc[mi][ni][3] + bv;
        {
          bf16x4 o = { (bf16)v0, (bf16)v1, (bf16)v2, (bf16)v3 };
          *(bf16x4*)(vt0 + (size_t)((seg0 * 16 + h) * 64 + d) * 1024 + kt0 + nw0) = o;
        }
        {
          const float a = grp1 ? v1 : v0;    // r = grp1
          const float b = grp1 ? v3 : v2;    // r = grp1 + 2
          bf16x2 o = { (bf16)a, (bf16)b };
          *(bf16x2*)(vt1 + (size_t)((seg1 * 16 + h) * 64 + d) * 1024 + kt1 + nw1) = o;
        }
        {
          const float a = (grp2 == 0) ? v0 : (grp2 == 1) ? v1
                         : (grp2 == 2) ? v2 : v3;            // r = grp2
          vt2[(size_t)(h * 64 + d) * 1024 + kt2 + nw2] = (bf16)a;
        }
      }
    }
  }
}

__global__ __launch_bounds__(256) void gemm_qkv_kernel(
    const float* q, const float* k, const float* v,
    const float* wq, const float* wk, const float* wv,
    const float* bq, const float* bk, const float* bv,
    bf16* qo, bf16* ko,
    bf16* vt0, bf16* vt1, bf16* vt2)
{
  if (blockIdx.z == 0)
    gemm_body<bf16, true, true>(q, wq, bq, qo, nullptr, nullptr, nullptr, false);
  else if (blockIdx.z == 1)
    gemm_body<bf16, true, true>(k, wk, bk, ko, nullptr, nullptr, nullptr, false);
  else
    gemm_body<bf16, true, true>(v, wv, bv, (bf16*)nullptr, vt0, vt1, vt2, true);
}

__global__ __launch_bounds__(256) void gemm_out_kernel(
    const bf16* A, const float* W, const float* bias, float* C)
{
  gemm_body<float, false, true>(A, W, bias, C, nullptr, nullptr, nullptr, false);
}

// ---------------------------------------------------------------------------
// Flash attention, transposed-S form with XOR-swizzled LDS tiles.
// Block = (branch, seg, h, pair j): q-tiles qtA = 15-j and qtB = j over one
// shared staged K/V stream. Dual-tile fused compute: both tiles consume the
// SAME K/V fragments, softmax chains interleave. l-sum via ones-MFMA.
// ---------------------------------------------------------------------------
__global__ __launch_bounds__(256, 4) void attn_kernel(
    const bf16* __restrict__ qg, const bf16* __restrict__ kg,
    const bf16* vt0, const bf16* vt1, const bf16* vt2,
    bf16* o0, bf16* o1, bf16* o2,
    float* l0, float* l1, float* l2)
{
  __shared__ __align__(16) bf16 lK[2][64 * 64];     // [kj][d], swizzled
  __shared__ __align__(16) bf16 lV[2][64 * 64];     // [d][kj'], swizzled

  // XCD-affinity remap (bijective, 896 = 8*112): hardware assigns block b to
  // XCD b%8; logical id o = (b&7)*112 + (b>>3) gives each XCD a contiguous
  // run of 112 logical blocks = 14 (seg,h) groups -> K/V fits that XCD's L2.
  const int bid0 = blockIdx.x;
  const int o = (bid0 & 7) * 112 + (bid0 >> 3);

  int sl, dr, rem, shift;
  const bf16* vt; bf16* ob; float* lseb;
  if (o < 512)      { sl = 1024; dr = 1; rem = o;       vt = vt0; ob = o0; lseb = l0; shift = 4; }
  else if (o < 768) { sl = 2048; dr = 2; rem = o - 512; vt = vt1; ob = o1; lseb = l1; shift = 3; }
  else              { sl = 4096; dr = 4; rem = o - 768; vt = vt2; ob = o2; lseb = l2; shift = 2; }
  const int j   = rem & 7;
  const int h   = (rem >> 3) & 15;
  const int seg = rem >> 7;
  const int qtA = 15 - j;                // high q-tile (16-j k-iterations)
  const int qtB = j;                     // low q-tile  (j+1 k-iterations); qtB < qtA
  const int grp = h >> shift;
  const int segbase = seg * sl;

  const int tid = threadIdx.x, lane = tid & 63, w = tid >> 6;
  const int quad = lane >> 4, l16 = lane & 15;
  const int rs8 = l16 & 7;               // row-XOR term: (kj&7)==(drow&7)==l16&7

  // Q fragments (B-operand of S^T MFMA): B[k=d=quad*8+j][n=q=l16]
  auto loadq = [&](int qt, bf16x8& a0, bf16x8& a1) {
    const int qi = qt * 64 + w * 16 + l16;
    const size_t p = (size_t)(segbase + qi * dr + grp);
    const bf16* qp = qg + p * EDIM + h * 64 + quad * 8;
    a0 = *(const bf16x8*)(qp);
    a1 = *(const bf16x8*)(qp + 32);
  };
  bf16x8 qaA0, qaA1, qaB0, qaB1;
  loadq(qtA, qaA0, qaA1);
  loadq(qtB, qaB0, qaB1);

  f32x4 OA[4] = {}, OB[4] = {};          // O^T frags: col l16=q, row = d
  f32x4 lsA = {0.f, 0.f, 0.f, 0.f};      // l accumulated by ones-MFMA
  f32x4 lsB = {0.f, 0.f, 0.f, 0.f};
  float mA = -__builtin_inff();          // m in log2 units
  float mB = -__builtin_inff();
  const bf16x4 ONES = { (bf16)1.f, (bf16)1.f, (bf16)1.f, (bf16)1.f };

  const bf16* vbase = vt + (size_t)(seg * NH + h) * 64 * GLEN;
  const int c0 = tid, c1 = tid + 256;
  // staging-source permutation implementing the XOR swizzle:
  // LDS chunk position p (=c0/c1) is row r=p>>3, slot s=p&7; it must receive
  // global chunk c = s ^ (r & 7).
  const int r0 = c0 >> 3, sw0 = ((c0 & 7) ^ (r0 & 7));
  const int r1 = c1 >> 3, sw1 = ((c1 & 7) ^ (r1 & 7));

  // incremental staging pointers (advance one k-tile per stage call)
  const bf16* kp0 = kg + (size_t)(segbase + r0 * dr + grp) * EDIM + h * 64 + sw0 * 8;
  const bf16* kp1 = kg + (size_t)(segbase + r1 * dr + grp) * EDIM + h * 64 + sw1 * 8;
  const bf16* vp0 = vbase + (size_t)r0 * GLEN + sw0 * 8;
  const bf16* vp1 = vbase + (size_t)r1 * GLEN + sw1 * 8;
  const size_t kstep = (size_t)64 * dr * EDIM;

  auto stage = [&](int buf) {
    gload16(kp0, &lK[buf][c0 * 8]);
    gload16(kp1, &lK[buf][c1 * 8]);
    gload16(vp0, &lV[buf][c0 * 8]);
    gload16(vp1, &lV[buf][c1 * 8]);
    kp0 += kstep; kp1 += kstep; vp0 += 64; vp1 += 64;
  };

  const float CS = 0.18033688011112042f;   // (1/sqrt(64)) * log2(e)
  const float NEGINF = -__builtin_inff();
  const int qiA = qtA * 64 + w * 16 + l16;
  const int qiB = qtB * 64 + w * 16 + l16;

  // loop-invariant LDS read bases (K: kj = t*16+l16 -> +t*1024; V: +nf*1024)
  const int kb0 = l16 * 64 + ((quad ^ rs8) * 8);
  const int kb1 = l16 * 64 + (((4 + quad) ^ rs8) * 8);
  const int vb0 = l16 * 64;

  // Fused dual-tile compute. HAS_B: tile B active this k-tile. DIAG_A/B:
  // causal-diagonal masking for that tile (DIAG_A implies !HAS_B).
  auto comp = [&](auto hasB_, auto diagA_, auto diagB_, int kt) {
    constexpr bool HAS_B  = decltype(hasB_)::v;
    constexpr bool DIAG_A = decltype(diagA_)::v;
    constexpr bool DIAG_B = decltype(diagB_)::v;
    const bf16* bK = lK[kt & 1];
    const bf16* bV = lV[kt & 1];

    // --- S^T = K Q^T for both tiles off shared K fragments ---
    f32x4 sA[4], sB[4];
#pragma unroll
    for (int t = 0; t < 4; t++) {
      const bool aA = !DIAG_A || t <= w;
      const bool aB = HAS_B && (!DIAG_B || t <= w);
      if (aA || aB) {
        bf16x8 ka0 = *(const bf16x8*)&bK[kb0 + t * 1024];
        bf16x8 ka1 = *(const bf16x8*)&bK[kb1 + t * 1024];
        if (aA) {
          sA[t] = f32x4{0.f, 0.f, 0.f, 0.f};
          sA[t] = __builtin_amdgcn_mfma_f32_16x16x32_bf16(ka0, qaA0, sA[t], 0, 0, 0);
          sA[t] = __builtin_amdgcn_mfma_f32_16x16x32_bf16(ka1, qaA1, sA[t], 0, 0, 0);
        }
        if (aB) {
          sB[t] = f32x4{0.f, 0.f, 0.f, 0.f};
          sB[t] = __builtin_amdgcn_mfma_f32_16x16x32_bf16(ka0, qaB0, sB[t], 0, 0, 0);
          sB[t] = __builtin_amdgcn_mfma_f32_16x16x32_bf16(ka1, qaB1, sB[t], 0, 0, 0);
        }
      }
    }

    // --- masked raw max, vector partials ---
    f32x4 mvA = {NEGINF, NEGINF, NEGINF, NEGINF};
    f32x4 mvB = {NEGINF, NEGINF, NEGINF, NEGINF};
#pragma unroll
    for (int t = 0; t < 4; t++) {
      if (!DIAG_A || t <= w) {
#pragma unroll
        for (int r = 0; r < 4; r++) {
          float sv = sA[t][r];
          if (DIAG_A) {
            const int kj = kt * 64 + t * 16 + quad * 4 + r;
            if (kj > qiA) sv = NEGINF;
          }
          sA[t][r] = sv;
          mvA[r] = fmaxf(mvA[r], sv);
        }
      }
      if (HAS_B && (!DIAG_B || t <= w)) {
#pragma unroll
        for (int r = 0; r < 4; r++) {
          float sv = sB[t][r];
          if (DIAG_B) {
            const int kj = kt * 64 + t * 16 + quad * 4 + r;
            if (kj > qiB) sv = NEGINF;
          }
          sB[t][r] = sv;
          mvB[r] = fmaxf(mvB[r], sv);
        }
      }
    }
    float mrA = fmaxf(fmaxf(mvA[0], mvA[1]), fmaxf(mvA[2], mvA[3]));
    float mrB = fmaxf(fmaxf(mvB[0], mvB[1]), fmaxf(mvB[2], mvB[3]));
    mrA = fmaxf(mrA, __shfl_xor(mrA, 16, 64));
    mrA = fmaxf(mrA, __shfl_xor(mrA, 32, 64));
    if constexpr (HAS_B) {
      mrB = fmaxf(mrB, __shfl_xor(mrB, 16, 64));
      mrB = fmaxf(mrB, __shfl_xor(mrB, 32, 64));
    }

    // --- defer-rescale (T13), wave-uniform skip ---
    {
      const float mnew = fmaxf(mA, mrA * CS);
      if (!__all(mnew - mA <= 8.0f)) {
        const float alpha = fast_exp2(mA - mnew);   // first tile: exp2(-inf)=0
#pragma unroll
        for (int nf = 0; nf < 4; nf++)
#pragma unroll
          for (int r = 0; r < 4; r++) OA[nf][r] *= alpha;
#pragma unroll
        for (int r = 0; r < 4; r++) lsA[r] *= alpha;
        mA = mnew;
      }
    }
    if constexpr (HAS_B) {
      const float mnew = fmaxf(mB, mrB * CS);
      if (!__all(mnew - mB <= 8.0f)) {
        const float alpha = fast_exp2(mB - mnew);
#pragma unroll
        for (int nf = 0; nf < 4; nf++)
#pragma unroll
          for (int r = 0; r < 4; r++) OB[nf][r] *= alpha;
#pragma unroll
        for (int r = 0; r < 4; r++) lsB[r] *= alpha;
        mB = mnew;
      }
    }

    // --- p = exp2(fma(s_raw, CS, -m)) <= 2^8; bf16 pack ---
    bf16x4 pbA[4], pbB[4];
#pragma unroll
    for (int t = 0; t < 4; t++) {
      if (!DIAG_A || t <= w) {
#pragma unroll
        for (int r = 0; r < 4; r++)
          pbA[t][r] = (bf16)fast_exp2(__builtin_fmaf(sA[t][r], CS, -mA));
      }
      if (HAS_B && (!DIAG_B || t <= w)) {
#pragma unroll
        for (int r = 0; r < 4; r++)
          pbB[t][r] = (bf16)fast_exp2(__builtin_fmaf(sB[t][r], CS, -mB));
      }
    }

    // --- O^T += V^T P^T off shared V fragments (paired b128 reads);
    //     l += ones-MFMA(P^T): full 64-kpos row sum incl. cross-quad ---
#pragma unroll
    for (int p2 = 0; p2 < 2; p2++) {
      const int t0 = 2 * p2, t1 = t0 + 1;
      const bool aA0 = !DIAG_A || t0 <= w;
      const bool aA1 = !DIAG_A || t1 <= w;
      const bool aB0 = HAS_B && (!DIAG_B || t0 <= w);
      const bool aB1 = HAS_B && (!DIAG_B || t1 <= w);
      if (aA0 || aA1 || aB0 || aB1) {
        const int cx = ((p2 * 4 + quad) ^ rs8) * 8;
#pragma unroll
        for (int nf = 0; nf < 4; nf++) {
          bf16x8 va8 = *(const bf16x8*)&bV[vb0 + nf * 1024 + cx];
          bf16x4 vlo = __builtin_shufflevector(va8, va8, 0, 1, 2, 3);
          bf16x4 vhi = __builtin_shufflevector(va8, va8, 4, 5, 6, 7);
          if (aA0) OA[nf] = mfma16x16x16_bf16(vlo, pbA[t0], OA[nf]);
          if (aA1) OA[nf] = mfma16x16x16_bf16(vhi, pbA[t1], OA[nf]);
          if (aB0) OB[nf] = mfma16x16x16_bf16(vlo, pbB[t0], OB[nf]);
          if (aB1) OB[nf] = mfma16x16x16_bf16(vhi, pbB[t1], OB[nf]);
        }
        if (aA0) lsA = mfma16x16x16_bf16(ONES, pbA[t0], lsA);
        if (aA1) lsA = mfma16x16x16_bf16(ONES, pbA[t1], lsA);
        if (aB0) lsB = mfma16x16x16_bf16(ONES, pbB[t0], lsB);
        if (aB1) lsB = mfma16x16x16_bf16(ONES, pbB[t1], lsB);
      }
    }
  };

  stage(0);
  int kt = 0;
  // Phase 1: both tiles, no diagonal (kt < qtB)
  for (; kt < qtB; kt++) {
    __syncthreads();
    stage((kt + 1) & 1);
    comp(Flag<true>{}, Flag<false>{}, Flag<false>{}, kt);
  }
  // kt == qtB: tile A full, tile B diagonal (qtB < qtA always)
  __syncthreads();
  stage((kt + 1) & 1);
  comp(Flag<true>{}, Flag<false>{}, Flag<true>{}, kt);
  kt++;
  // Phase 2: tile A only (qtB < kt < qtA)
  for (; kt < qtA; kt++) {
    __syncthreads();
    stage((kt + 1) & 1);
    comp(Flag<false>{}, Flag<false>{}, Flag<false>{}, kt);
  }
  // kt == qtA: tile A diagonal
  __syncthreads();
  comp(Flag<false>{}, Flag<true>{}, Flag<false>{}, kt);

  // epilogue: lane l16 owns q column; d = nf*16 + quad*4 + r (4 contiguous)
  auto epilogue = [&](const f32x4 (&Oa)[4], float m_r, float l_r, int qt) {
    const int qi = qt * 64 + w * 16 + l16;
    const float linv = 1.0f / l_r;
    const int pdense = segbase + qi * dr + grp;
    bf16* orow = ob + (size_t)pdense * EDIM + h * 64;
#pragma unroll
    for (int nf = 0; nf < 4; nf++) {
      bf16x4 ov;
#pragma unroll
      for (int r = 0; r < 4; r++) ov[r] = (bf16)(Oa[nf][r] * linv);
      *(bf16x4*)(orow + nf * 16 + quad * 4) = ov;
    }
    if (quad == 0)
      lseb[h * L_SEQ + pdense] = m_r * 0.6931471805599453f + __logf(l_r);
  };
  epilogue(OA, mA, lsA[0], qtA);
  epilogue(OB, mB, lsB[0], qtB);
}

// ---------------------------------------------------------------------------
// Merge: softmax over branch lse at each (h,p); coverage computed analytically.
// ---------------------------------------------------------------------------
__global__ __launch_bounds__(256) void merge_kernel(
    const bf16* __restrict__ o0, const bf16* __restrict__ o1, const bf16* __restrict__ o2,
    const float* __restrict__ l0, const float* __restrict__ l1, const float* __restrict__ l2,
    bf16* __restrict__ merged)
{
  const int idx = blockIdx.x * 256 + threadIdx.x;   // over L*H*8
  const int dc = idx & 7;
  const int h  = (idx >> 3) & 15;
  const int p  = idx >> 7;
  const bool c1 = ((p & 1) == (h >> 3));   // branch dr=2 coverage
  const bool c2 = ((p & 3) == (h >> 2));   // branch dr=4 coverage
  const float s0 = l0[h * L_SEQ + p];
  const float s1 = c1 ? l1[h * L_SEQ + p] : -__builtin_inff();
  const float s2 = c2 ? l2[h * L_SEQ + p] : -__builtin_inff();
  const float mx = fmaxf(s0, fmaxf(s1, s2));
  float w0 = __expf(s0 - mx);
  float w1 = c1 ? __expf(s1 - mx) : 0.f;
  float w2 = c2 ? __expf(s2 - mx) : 0.f;
  const float inv = 1.0f / (w0 + w1 + w2);
  w0 *= inv; w1 *= inv; w2 *= inv;

  const size_t off = (size_t)p * EDIM + h * 64 + dc * 8;
  float acc[8];
  bf16x8 a0 = *(const bf16x8*)(o0 + off);
#pragma unroll
  for (int j = 0; j < 8; j++) acc[j] = w0 * (float)a0[j];
  if (c1) {
    bf16x8 a1 = *(const bf16x8*)(o1 + off);
#pragma unroll
    for (int j = 0; j < 8; j++) acc[j] += w1 * (float)a1[j];
  }
  if (c2) {
    bf16x8 a2 = *(const bf16x8*)(o2 + off);
#pragma unroll
    for (int j = 0; j < 8; j++) acc[j] += w2 * (float)a2[j];
  }
  bf16x8 r;
#pragma unroll
  for (int j = 0; j < 8; j++) r[j] = (bf16)acc[j];
  *(bf16x8*)(merged + off) = r;
}

// ---------------------------------------------------------------------------
extern "C" void kernel_launch(void* const* d_in, const int* in_sizes, int n_in,
                              void* d_out, int out_size, void* d_ws, size_t ws_size,
                              hipStream_t stream)
{
  (void)in_sizes; (void)n_in; (void)out_size; (void)ws_size;
  const float* query = (const float*)d_in[0];
  const float* key   = (const float*)d_in[1];
  const float* value = (const float*)d_in[2];
  const float* Wq = (const float*)d_in[3];
  const float* bq = (const float*)d_in[4];
  const float* Wk = (const float*)d_in[5];
  const float* bk = (const float*)d_in[6];
  const float* Wv = (const float*)d_in[7];
  const float* bv = (const float*)d_in[8];
  const float* Wo = (const float*)d_in[9];
  const float* bo = (const float*)d_in[10];

  char* base = (char*)d_ws;
  size_t off = 0;
  auto take = [&](size_t nbytes) -> char* {
    char* p = base + off;
    off += (nbytes + 255) & ~(size_t)255;
    return p;
  };
  const size_t LE2 = (size_t)L_SEQ * EDIM * 2;
  bf16* qb  = (bf16*)take(LE2);
  bf16* kb  = (bf16*)take(LE2);
  bf16* o0  = (bf16*)take(LE2);
  bf16* o1  = (bf16*)take(LE2);
  bf16* o2  = (bf16*)take(LE2);
  bf16* vt0 = (bf16*)take((size_t)4 * NH * HD * GLEN * 2);
  bf16* vt1 = (bf16*)take((size_t)2 * NH * HD * GLEN * 2);
  bf16* vt2 = (bf16*)take((size_t)1 * NH * HD * GLEN * 2);
  float* lse0 = (float*)take((size_t)NH * L_SEQ * 4);
  float* lse1 = (float*)take((size_t)NH * L_SEQ * 4);
  float* lse2 = (float*)take((size_t)NH * L_SEQ * 4);
  bf16* merged = (bf16*)take(LE2);

  dim3 blk(256);
  gemm_qkv_kernel<<<dim3(8, 32, 3), blk, 0, stream>>>(
      query, key, value, Wq, Wk, Wv, bq, bk, bv, qb, kb, vt0, vt1, vt2);
  attn_kernel<<<dim3(896), blk, 0, stream>>>(
      qb, kb, vt0, vt1, vt2, o0, o1, o2, lse0, lse1, lse2);
  merge_kernel<<<dim3(2048), blk, 0, stream>>>(
      o0, o1, o2, lse0, lse1, lse2, merged);
  gemm_out_kernel<<<dim3(8, 32), blk, 0, stream>>>(merged, Wo, bo, (float*)d_out);
}

// Round 12
// 216.152 us; speedup vs baseline: 2.3450x; 1.1385x over previous
//
#include <hip/hip_runtime.h>
#include <math.h>

// DilatedAttention on MI355X (gfx950), bf16 MFMA implementation.
// L=4096, E=1024, H=16, D=64. Branches (sl,dr) = (1024,1),(2048,2),(4096,4).
// Every branch reduces to causal attention over g=1024 sparse positions.
//
// Attention in transposed-S form:
//   S^T = K Q^T  (lane l16 = q column)
//   O^T = V^T P^T with 16x16x16 MFMA    -> P^T registers are the B-operand.
// R4: XOR-swizzled attn LDS tiles via staging-source permutation.
// R5: q-tile PAIR (j, 15-j) per block: exactly 17 tile-computes each.
// R6: fused dual-tile compute (shared K/V fragments, interleaved chains).
// R7: GEMM/attn XCD-affinity remaps; V^T pair-permuted (bank conflicts -> 0).
// R8: attn l-sum via ones-MFMA; setprio removed (measured regression).
// R9-R11 (FAILED/NULL): reg-staged cvt fusion; T3/T4 pipelining on 128² GEMM.
// R12 (BEST, 217.4us): vtrans fused into gemm_qkv V epilogue (5 launches).
// R13/R14 (REGRESSED 507/246us): fp32 GEMM operands -- even conflict-free
// (R14 swizzle cut SQ_LDS_BANK_CONFLICT 1.37e8 -> 6.3M), the doubled
// staging volume costs ~35us in the GEMMs vs 22us saved. Branch CLOSED.
// R15 (COMPILE ERROR): R12 revert passed fp32 Wo to bf16 gemm_out param.
// R16: same revert, fixed -- gemm_out consumes the cvt'd bf16 wob.
// Component ledger: cvt 16us (BW floor) + gemm_qkv 42.5 (scheduling
// plateau, R10/R11 nulls) + attn ~42 (7 applied opts) + merge 6 (BW floor)
// + gemm_out ~16 + ~95us fixed inter-dispatch overhead.

#define L_SEQ 4096
#define EDIM  1024
#define NH    16
#define HD    64
#define GLEN  1024

typedef __bf16 bf16;
typedef __bf16 bf16x8 __attribute__((ext_vector_type(8)));
typedef __bf16 bf16x4 __attribute__((ext_vector_type(4)));
typedef __bf16 bf16x2 __attribute__((ext_vector_type(2)));
typedef short  s16x4  __attribute__((ext_vector_type(4)));
typedef float  f32x4  __attribute__((ext_vector_type(4)));

template <bool B> struct Flag { static constexpr bool v = B; };

// async global->LDS, 16B per lane. LDS dest semantics: wave-uniform base + lane*16.
__device__ __forceinline__ void gload16(const bf16* g, bf16* l) {
  __builtin_amdgcn_global_load_lds(
      (__attribute__((address_space(1))) void*)(const_cast<bf16*>(g)),
      (__attribute__((address_space(3))) void*)(l),
      16, 0, 0);
}

// v_mfma_f32_16x16x16_bf16 (builtin name only exists in the device pass).
__device__ __forceinline__ f32x4 mfma16x16x16_bf16(bf16x4 a, bf16x4 b, f32x4 c) {
#if defined(__HIP_DEVICE_COMPILE__)
  union { bf16x4 h; s16x4 s; } ua, ub;
  ua.h = a; ub.h = b;
  return __builtin_amdgcn_mfma_f32_16x16x16bf16_1k(ua.s, ub.s, c, 0, 0, 0);
#else
  (void)a; (void)b;
  return c;   // host stub, never executed
#endif
}

__device__ __forceinline__ float fast_exp2(float x) {
#if __has_builtin(__builtin_amdgcn_exp2f)
  return __builtin_amdgcn_exp2f(x);
#else
  return __expf(x * 0.6931471805599453f);
#endif
}

// ---------------------------------------------------------------------------
// fp32 -> bf16 conversion, exact-cover 1D grid (8192 blocks x 256 x 8 elems):
// elems [0,12M): q/k/v (4M=2^22 each); [12M,16M): Wq/Wk/Wv/Wo (1M=2^20 each).
// ---------------------------------------------------------------------------
__global__ __launch_bounds__(256) void cvt_kernel(
    const float* q, const float* k, const float* v,
    const float* wq, const float* wk, const float* wv, const float* wo,
    bf16* oq, bf16* ok, bf16* ov,
    bf16* owq, bf16* owk, bf16* owv, bf16* owo)
{
  const size_t e = ((size_t)blockIdx.x * 256 + threadIdx.x) * 8;
  const float* src; bf16* dst; size_t off;
  if (e < (size_t)12 * 1024 * 1024) {
    const int s = (int)(e >> 22);
    off = e & (((size_t)1 << 22) - 1);
    src = (s == 0) ? q : (s == 1) ? k : v;
    dst = (s == 0) ? oq : (s == 1) ? ok : ov;
  } else {
    const size_t e2 = e - (size_t)12 * 1024 * 1024;
    const int s = (int)(e2 >> 20);
    off = e2 & (((size_t)1 << 20) - 1);
    src = (s == 0) ? wq : (s == 1) ? wk : (s == 2) ? wv : wo;
    dst = (s == 0) ? owq : (s == 1) ? owk : (s == 2) ? owv : owo;
  }
  const float4* s4 = (const float4*)(src + off);
  float4 a = s4[0], b = s4[1];
  bf16x8 o = { (bf16)a.x, (bf16)a.y, (bf16)a.z, (bf16)a.w,
               (bf16)b.x, (bf16)b.y, (bf16)b.z, (bf16)b.w };
  *(bf16x8*)(dst + off) = o;
}

// ---------------------------------------------------------------------------
// GEMM: C[m][n] = sum_k A[m][k] * W[n][k] + bias[n]   (B^T layout)
// M=4096, N=1024, K=1024. 128x128 tile, BK=32, 4 waves (2x2 of 64x64),
// 16x16x32 bf16 MFMA, global_load_lds staging, 2-barrier loop (measured
// plateau; R10/R11 pipelining variants were null/worse).
// Grid MUST be (8, 32[, z]); XCD-affinity: HW XCD = flat%8 = blockIdx.x;
// XCD x owns row-panels [x*4, x*4+4) (A panels hit one XCD L2).
// vfuse: V-instance epilogue writes directly into the 3 per-branch
// vt layouts (vt_b[seg][h][d][kj'] with kj' pair-permuted) instead of C.
// pair-permute: nw(kj) = (t16>>1)*32 + (j16>>2)*8 + (t16&1)*4 + (j16&3),
// t16 = (kj>>4)&3, j16 = kj&15 (matches the old vtrans layout exactly).
// ---------------------------------------------------------------------------
template <typename OutT>
__device__ __forceinline__ void gemm_body(const bf16* __restrict__ A,
                                          const bf16* __restrict__ W,
                                          const float* __restrict__ bias,
                                          OutT* __restrict__ C,
                                          bf16* __restrict__ vt0,
                                          bf16* __restrict__ vt1,
                                          bf16* __restrict__ vt2,
                                          const bool vfuse)
{
  constexpr int K = 1024;
  __shared__ __align__(16) bf16 lA[128 * 32];
  __shared__ __align__(16) bf16 lB[128 * 32];

  const int tid  = threadIdx.x;
  const int lane = tid & 63;
  const int w    = tid >> 6;
  const int quad = lane >> 4;
  const int l16  = lane & 15;
  const int wr   = w >> 1, wc = w & 1;
  // XCD-affinity remap (bijective over 8x32): ly=x*4+(y>>3), lx=y&7
  const int ly = blockIdx.x * 4 + (blockIdx.y >> 3);
  const int lx = blockIdx.y & 7;
  const int row0 = ly * 128;
  const int col0 = lx * 128;

  f32x4 acc[4][4] = {};

  const int c0 = tid, c1 = tid + 256;
  const bf16* Ab0 = A + (size_t)(row0 + (c0 >> 2)) * K + (c0 & 3) * 8;
  const bf16* Ab1 = A + (size_t)(row0 + (c1 >> 2)) * K + (c1 & 3) * 8;
  const bf16* Bb0 = W + (size_t)(col0 + (c0 >> 2)) * K + (c0 & 3) * 8;
  const bf16* Bb1 = W + (size_t)(col0 + (c1 >> 2)) * K + (c1 & 3) * 8;

  for (int kt = 0; kt < K; kt += 32) {
    __syncthreads();
    gload16(Ab0 + kt, &lA[c0 * 8]);
    gload16(Ab1 + kt, &lA[c1 * 8]);
    gload16(Bb0 + kt, &lB[c0 * 8]);
    gload16(Bb1 + kt, &lB[c1 * 8]);
    __syncthreads();

    bf16x8 af[4], bfrag[4];
#pragma unroll
    for (int mi = 0; mi < 4; mi++)
      af[mi] = *(const bf16x8*)&lA[(wr * 64 + mi * 16 + l16) * 32 + quad * 8];
#pragma unroll
    for (int ni = 0; ni < 4; ni++)
      bfrag[ni] = *(const bf16x8*)&lB[(wc * 64 + ni * 16 + l16) * 32 + quad * 8];
#pragma unroll
    for (int mi = 0; mi < 4; mi++)
#pragma unroll
      for (int ni = 0; ni < 4; ni++)
        acc[mi][ni] = __builtin_amdgcn_mfma_f32_16x16x32_bf16(
            af[mi], bfrag[ni], acc[mi][ni], 0, 0, 0);
  }

  if (!vfuse) {
#pragma unroll
    for (int mi = 0; mi < 4; mi++) {
#pragma unroll
      for (int ni = 0; ni < 4; ni++) {
        const int gcol = col0 + wc * 64 + ni * 16 + l16;
        const float bv = bias[gcol];
#pragma unroll
        for (int r = 0; r < 4; r++) {
          const int grow = row0 + wr * 64 + mi * 16 + quad * 4 + r;
          C[(size_t)grow * 1024 + gcol] = (OutT)(acc[mi][ni][r] + bv);
        }
      }
    }
  } else {
    // V-instance: scatter biased C directly into vt0/vt1/vt2.
    const int h    = 2 * lx + wc;          // this wave's head (cols h*64..h*64+63)
    const int grp1 = h >> 3, grp2 = h >> 2;
#pragma unroll
    for (int mi = 0; mi < 4; mi++) {
      const int p0 = row0 + wr * 64 + mi * 16 + quad * 4;   // aligned 4
      // branch 0 (dr=1, sl=1024): kj = pos0 + r
      const int seg0 = p0 >> 10;
      const int pos0 = p0 & 1023;
      const int nw0  = ((pos0 >> 5) & 1) * 32 + ((pos0 >> 2) & 3) * 8
                     + ((pos0 >> 4) & 1) * 4;                // (pos0&3)==0
      const int kt0  = (pos0 >> 6) * 64;
      // branch 1 (dr=2, sl=2048): kept r in {grp1, grp1+2}; kj = kja, kja+1
      const int seg1 = p0 >> 11;
      const int kja  = (p0 & 2047) >> 1;                     // aligned 2
      const int nw1  = ((kja >> 5) & 1) * 32 + ((kja >> 2) & 3) * 8
                     + ((kja >> 4) & 1) * 4 + (kja & 3);     // even
      const int kt1  = (kja >> 6) * 64;
      // branch 2 (dr=4, sl=4096): kept r = grp2; kj2 = p0>>2
      const int kj2  = p0 >> 2;
      const int nw2  = ((kj2 >> 5) & 1) * 32 + ((kj2 >> 2) & 3) * 8
                     + ((kj2 >> 4) & 1) * 4 + (kj2 & 3);
      const int kt2  = (kj2 >> 6) * 64;
#pragma unroll
      for (int ni = 0; ni < 4; ni++) {
        const int d  = ni * 16 + l16;
        const float bv = bias[col0 + wc * 64 + d];
        const float v0 = acc[mi][ni][0] + bv;
        const float v1 = acc[mi][ni][1] + bv;
        const float v2 = acc[mi][ni][2] + bv;
        const float v3 = acc[mi][ni][3] + bv;
        {
          bf16x4 o = { (bf16)v0, (bf16)v1, (bf16)v2, (bf16)v3 };
          *(bf16x4*)(vt0 + (size_t)((seg0 * 16 + h) * 64 + d) * 1024 + kt0 + nw0) = o;
        }
        {
          const float a = grp1 ? v1 : v0;    // r = grp1
          const float b = grp1 ? v3 : v2;    // r = grp1 + 2
          bf16x2 o = { (bf16)a, (bf16)b };
          *(bf16x2*)(vt1 + (size_t)((seg1 * 16 + h) * 64 + d) * 1024 + kt1 + nw1) = o;
        }
        {
          const float a = (grp2 == 0) ? v0 : (grp2 == 1) ? v1
                         : (grp2 == 2) ? v2 : v3;            // r = grp2
          vt2[(size_t)(h * 64 + d) * 1024 + kt2 + nw2] = (bf16)a;
        }
      }
    }
  }
}

__global__ __launch_bounds__(256) void gemm_qkv_kernel(
    const bf16* xq, const bf16* xk, const bf16* xv,
    const bf16* wq, const bf16* wk, const bf16* wv,
    const float* bq, const float* bk, const float* bv,
    bf16* q, bf16* k,
    bf16* vt0, bf16* vt1, bf16* vt2)
{
  if (blockIdx.z == 0)
    gemm_body<bf16>(xq, wq, bq, q, nullptr, nullptr, nullptr, false);
  else if (blockIdx.z == 1)
    gemm_body<bf16>(xk, wk, bk, k, nullptr, nullptr, nullptr, false);
  else
    gemm_body<bf16>(xv, wv, bv, (bf16*)nullptr, vt0, vt1, vt2, true);
}

__global__ __launch_bounds__(256) void gemm_out_kernel(
    const bf16* A, const bf16* W, const float* bias, float* C)
{
  gemm_body<float>(A, W, bias, C, nullptr, nullptr, nullptr, false);
}

// ---------------------------------------------------------------------------
// Flash attention, transposed-S form with XOR-swizzled LDS tiles.
// Block = (branch, seg, h, pair j): q-tiles qtA = 15-j and qtB = j over one
// shared staged K/V stream. Dual-tile fused compute: both tiles consume the
// SAME K/V fragments, softmax chains interleave. l-sum via ones-MFMA.
// ---------------------------------------------------------------------------
__global__ __launch_bounds__(256, 4) void attn_kernel(
    const bf16* __restrict__ qg, const bf16* __restrict__ kg,
    const bf16* vt0, const bf16* vt1, const bf16* vt2,
    bf16* o0, bf16* o1, bf16* o2,
    float* l0, float* l1, float* l2)
{
  __shared__ __align__(16) bf16 lK[2][64 * 64];     // [kj][d], swizzled
  __shared__ __align__(16) bf16 lV[2][64 * 64];     // [d][kj'], swizzled

  // XCD-affinity remap (bijective, 896 = 8*112): hardware assigns block b to
  // XCD b%8; logical id o = (b&7)*112 + (b>>3) gives each XCD a contiguous
  // run of 112 logical blocks = 14 (seg,h) groups -> K/V fits that XCD's L2.
  const int bid0 = blockIdx.x;
  const int o = (bid0 & 7) * 112 + (bid0 >> 3);

  int sl, dr, rem, shift;
  const bf16* vt; bf16* ob; float* lseb;
  if (o < 512)      { sl = 1024; dr = 1; rem = o;       vt = vt0; ob = o0; lseb = l0; shift = 4; }
  else if (o < 768) { sl = 2048; dr = 2; rem = o - 512; vt = vt1; ob = o1; lseb = l1; shift = 3; }
  else              { sl = 4096; dr = 4; rem = o - 768; vt = vt2; ob = o2; lseb = l2; shift = 2; }
  const int j   = rem & 7;
  const int h   = (rem >> 3) & 15;
  const int seg = rem >> 7;
  const int qtA = 15 - j;                // high q-tile (16-j k-iterations)
  const int qtB = j;                     // low q-tile  (j+1 k-iterations); qtB < qtA
  const int grp = h >> shift;
  const int segbase = seg * sl;

  const int tid = threadIdx.x, lane = tid & 63, w = tid >> 6;
  const int quad = lane >> 4, l16 = lane & 15;
  const int rs8 = l16 & 7;               // row-XOR term: (kj&7)==(drow&7)==l16&7

  // Q fragments (B-operand of S^T MFMA): B[k=d=quad*8+j][n=q=l16]
  auto loadq = [&](int qt, bf16x8& a0, bf16x8& a1) {
    const int qi = qt * 64 + w * 16 + l16;
    const size_t p = (size_t)(segbase + qi * dr + grp);
    const bf16* qp = qg + p * EDIM + h * 64 + quad * 8;
    a0 = *(const bf16x8*)(qp);
    a1 = *(const bf16x8*)(qp + 32);
  };
  bf16x8 qaA0, qaA1, qaB0, qaB1;
  loadq(qtA, qaA0, qaA1);
  loadq(qtB, qaB0, qaB1);

  f32x4 OA[4] = {}, OB[4] = {};          // O^T frags: col l16=q, row = d
  f32x4 lsA = {0.f, 0.f, 0.f, 0.f};      // l accumulated by ones-MFMA
  f32x4 lsB = {0.f, 0.f, 0.f, 0.f};
  float mA = -__builtin_inff();          // m in log2 units
  float mB = -__builtin_inff();
  const bf16x4 ONES = { (bf16)1.f, (bf16)1.f, (bf16)1.f, (bf16)1.f };

  const bf16* vbase = vt + (size_t)(seg * NH + h) * 64 * GLEN;
  const int c0 = tid, c1 = tid + 256;
  // staging-source permutation implementing the XOR swizzle:
  // LDS chunk position p (=c0/c1) is row r=p>>3, slot s=p&7; it must receive
  // global chunk c = s ^ (r & 7).
  const int r0 = c0 >> 3, sw0 = ((c0 & 7) ^ (r0 & 7));
  const int r1 = c1 >> 3, sw1 = ((c1 & 7) ^ (r1 & 7));

  // incremental staging pointers (advance one k-tile per stage call)
  const bf16* kp0 = kg + (size_t)(segbase + r0 * dr + grp) * EDIM + h * 64 + sw0 * 8;
  const bf16* kp1 = kg + (size_t)(segbase + r1 * dr + grp) * EDIM + h * 64 + sw1 * 8;
  const bf16* vp0 = vbase + (size_t)r0 * GLEN + sw0 * 8;
  const bf16* vp1 = vbase + (size_t)r1 * GLEN + sw1 * 8;
  const size_t kstep = (size_t)64 * dr * EDIM;

  auto stage = [&](int buf) {
    gload16(kp0, &lK[buf][c0 * 8]);
    gload16(kp1, &lK[buf][c1 * 8]);
    gload16(vp0, &lV[buf][c0 * 8]);
    gload16(vp1, &lV[buf][c1 * 8]);
    kp0 += kstep; kp1 += kstep; vp0 += 64; vp1 += 64;
  };

  const float CS = 0.18033688011112042f;   // (1/sqrt(64)) * log2(e)
  const float NEGINF = -__builtin_inff();
  const int qiA = qtA * 64 + w * 16 + l16;
  const int qiB = qtB * 64 + w * 16 + l16;

  // loop-invariant LDS read bases (K: kj = t*16+l16 -> +t*1024; V: +nf*1024)
  const int kb0 = l16 * 64 + ((quad ^ rs8) * 8);
  const int kb1 = l16 * 64 + (((4 + quad) ^ rs8) * 8);
  const int vb0 = l16 * 64;

  // Fused dual-tile compute. HAS_B: tile B active this k-tile. DIAG_A/B:
  // causal-diagonal masking for that tile (DIAG_A implies !HAS_B).
  auto comp = [&](auto hasB_, auto diagA_, auto diagB_, int kt) {
    constexpr bool HAS_B  = decltype(hasB_)::v;
    constexpr bool DIAG_A = decltype(diagA_)::v;
    constexpr bool DIAG_B = decltype(diagB_)::v;
    const bf16* bK = lK[kt & 1];
    const bf16* bV = lV[kt & 1];

    // --- S^T = K Q^T for both tiles off shared K fragments ---
    f32x4 sA[4], sB[4];
#pragma unroll
    for (int t = 0; t < 4; t++) {
      const bool aA = !DIAG_A || t <= w;
      const bool aB = HAS_B && (!DIAG_B || t <= w);
      if (aA || aB) {
        bf16x8 ka0 = *(const bf16x8*)&bK[kb0 + t * 1024];
        bf16x8 ka1 = *(const bf16x8*)&bK[kb1 + t * 1024];
        if (aA) {
          sA[t] = f32x4{0.f, 0.f, 0.f, 0.f};
          sA[t] = __builtin_amdgcn_mfma_f32_16x16x32_bf16(ka0, qaA0, sA[t], 0, 0, 0);
          sA[t] = __builtin_amdgcn_mfma_f32_16x16x32_bf16(ka1, qaA1, sA[t], 0, 0, 0);
        }
        if (aB) {
          sB[t] = f32x4{0.f, 0.f, 0.f, 0.f};
          sB[t] = __builtin_amdgcn_mfma_f32_16x16x32_bf16(ka0, qaB0, sB[t], 0, 0, 0);
          sB[t] = __builtin_amdgcn_mfma_f32_16x16x32_bf16(ka1, qaB1, sB[t], 0, 0, 0);
        }
      }
    }

    // --- masked raw max, vector partials ---
    f32x4 mvA = {NEGINF, NEGINF, NEGINF, NEGINF};
    f32x4 mvB = {NEGINF, NEGINF, NEGINF, NEGINF};
#pragma unroll
    for (int t = 0; t < 4; t++) {
      if (!DIAG_A || t <= w) {
#pragma unroll
        for (int r = 0; r < 4; r++) {
          float sv = sA[t][r];
          if (DIAG_A) {
            const int kj = kt * 64 + t * 16 + quad * 4 + r;
            if (kj > qiA) sv = NEGINF;
          }
          sA[t][r] = sv;
          mvA[r] = fmaxf(mvA[r], sv);
        }
      }
      if (HAS_B && (!DIAG_B || t <= w)) {
#pragma unroll
        for (int r = 0; r < 4; r++) {
          float sv = sB[t][r];
          if (DIAG_B) {
            const int kj = kt * 64 + t * 16 + quad * 4 + r;
            if (kj > qiB) sv = NEGINF;
          }
          sB[t][r] = sv;
          mvB[r] = fmaxf(mvB[r], sv);
        }
      }
    }
    float mrA = fmaxf(fmaxf(mvA[0], mvA[1]), fmaxf(mvA[2], mvA[3]));
    float mrB = fmaxf(fmaxf(mvB[0], mvB[1]), fmaxf(mvB[2], mvB[3]));
    mrA = fmaxf(mrA, __shfl_xor(mrA, 16, 64));
    mrA = fmaxf(mrA, __shfl_xor(mrA, 32, 64));
    if constexpr (HAS_B) {
      mrB = fmaxf(mrB, __shfl_xor(mrB, 16, 64));
      mrB = fmaxf(mrB, __shfl_xor(mrB, 32, 64));
    }

    // --- defer-rescale (T13), wave-uniform skip ---
    {
      const float mnew = fmaxf(mA, mrA * CS);
      if (!__all(mnew - mA <= 8.0f)) {
        const float alpha = fast_exp2(mA - mnew);   // first tile: exp2(-inf)=0
#pragma unroll
        for (int nf = 0; nf < 4; nf++)
#pragma unroll
          for (int r = 0; r < 4; r++) OA[nf][r] *= alpha;
#pragma unroll
        for (int r = 0; r < 4; r++) lsA[r] *= alpha;
        mA = mnew;
      }
    }
    if constexpr (HAS_B) {
      const float mnew = fmaxf(mB, mrB * CS);
      if (!__all(mnew - mB <= 8.0f)) {
        const float alpha = fast_exp2(mB - mnew);
#pragma unroll
        for (int nf = 0; nf < 4; nf++)
#pragma unroll
          for (int r = 0; r < 4; r++) OB[nf][r] *= alpha;
#pragma unroll
        for (int r = 0; r < 4; r++) lsB[r] *= alpha;
        mB = mnew;
      }
    }

    // --- p = exp2(fma(s_raw, CS, -m)) <= 2^8; bf16 pack ---
    bf16x4 pbA[4], pbB[4];
#pragma unroll
    for (int t = 0; t < 4; t++) {
      if (!DIAG_A || t <= w) {
#pragma unroll
        for (int r = 0; r < 4; r++)
          pbA[t][r] = (bf16)fast_exp2(__builtin_fmaf(sA[t][r], CS, -mA));
      }
      if (HAS_B && (!DIAG_B || t <= w)) {
#pragma unroll
        for (int r = 0; r < 4; r++)
          pbB[t][r] = (bf16)fast_exp2(__builtin_fmaf(sB[t][r], CS, -mB));
      }
    }

    // --- O^T += V^T P^T off shared V fragments (paired b128 reads);
    //     l += ones-MFMA(P^T): full 64-kpos row sum incl. cross-quad ---
#pragma unroll
    for (int p2 = 0; p2 < 2; p2++) {
      const int t0 = 2 * p2, t1 = t0 + 1;
      const bool aA0 = !DIAG_A || t0 <= w;
      const bool aA1 = !DIAG_A || t1 <= w;
      const bool aB0 = HAS_B && (!DIAG_B || t0 <= w);
      const bool aB1 = HAS_B && (!DIAG_B || t1 <= w);
      if (aA0 || aA1 || aB0 || aB1) {
        const int cx = ((p2 * 4 + quad) ^ rs8) * 8;
#pragma unroll
        for (int nf = 0; nf < 4; nf++) {
          bf16x8 va8 = *(const bf16x8*)&bV[vb0 + nf * 1024 + cx];
          bf16x4 vlo = __builtin_shufflevector(va8, va8, 0, 1, 2, 3);
          bf16x4 vhi = __builtin_shufflevector(va8, va8, 4, 5, 6, 7);
          if (aA0) OA[nf] = mfma16x16x16_bf16(vlo, pbA[t0], OA[nf]);
          if (aA1) OA[nf] = mfma16x16x16_bf16(vhi, pbA[t1], OA[nf]);
          if (aB0) OB[nf] = mfma16x16x16_bf16(vlo, pbB[t0], OB[nf]);
          if (aB1) OB[nf] = mfma16x16x16_bf16(vhi, pbB[t1], OB[nf]);
        }
        if (aA0) lsA = mfma16x16x16_bf16(ONES, pbA[t0], lsA);
        if (aA1) lsA = mfma16x16x16_bf16(ONES, pbA[t1], lsA);
        if (aB0) lsB = mfma16x16x16_bf16(ONES, pbB[t0], lsB);
        if (aB1) lsB = mfma16x16x16_bf16(ONES, pbB[t1], lsB);
      }
    }
  };

  stage(0);
  int kt = 0;
  // Phase 1: both tiles, no diagonal (kt < qtB)
  for (; kt < qtB; kt++) {
    __syncthreads();
    stage((kt + 1) & 1);
    comp(Flag<true>{}, Flag<false>{}, Flag<false>{}, kt);
  }
  // kt == qtB: tile A full, tile B diagonal (qtB < qtA always)
  __syncthreads();
  stage((kt + 1) & 1);
  comp(Flag<true>{}, Flag<false>{}, Flag<true>{}, kt);
  kt++;
  // Phase 2: tile A only (qtB < kt < qtA)
  for (; kt < qtA; kt++) {
    __syncthreads();
    stage((kt + 1) & 1);
    comp(Flag<false>{}, Flag<false>{}, Flag<false>{}, kt);
  }
  // kt == qtA: tile A diagonal
  __syncthreads();
  comp(Flag<false>{}, Flag<true>{}, Flag<false>{}, kt);

  // epilogue: lane l16 owns q column; d = nf*16 + quad*4 + r (4 contiguous)
  auto epilogue = [&](const f32x4 (&Oa)[4], float m_r, float l_r, int qt) {
    const int qi = qt * 64 + w * 16 + l16;
    const float linv = 1.0f / l_r;
    const int pdense = segbase + qi * dr + grp;
    bf16* orow = ob + (size_t)pdense * EDIM + h * 64;
#pragma unroll
    for (int nf = 0; nf < 4; nf++) {
      bf16x4 ov;
#pragma unroll
      for (int r = 0; r < 4; r++) ov[r] = (bf16)(Oa[nf][r] * linv);
      *(bf16x4*)(orow + nf * 16 + quad * 4) = ov;
    }
    if (quad == 0)
      lseb[h * L_SEQ + pdense] = m_r * 0.6931471805599453f + __logf(l_r);
  };
  epilogue(OA, mA, lsA[0], qtA);
  epilogue(OB, mB, lsB[0], qtB);
}

// ---------------------------------------------------------------------------
// Merge: softmax over branch lse at each (h,p); coverage computed analytically.
// ---------------------------------------------------------------------------
__global__ __launch_bounds__(256) void merge_kernel(
    const bf16* __restrict__ o0, const bf16* __restrict__ o1, const bf16* __restrict__ o2,
    const float* __restrict__ l0, const float* __restrict__ l1, const float* __restrict__ l2,
    bf16* __restrict__ merged)
{
  const int idx = blockIdx.x * 256 + threadIdx.x;   // over L*H*8
  const int dc = idx & 7;
  const int h  = (idx >> 3) & 15;
  const int p  = idx >> 7;
  const bool c1 = ((p & 1) == (h >> 3));   // branch dr=2 coverage
  const bool c2 = ((p & 3) == (h >> 2));   // branch dr=4 coverage
  const float s0 = l0[h * L_SEQ + p];
  const float s1 = c1 ? l1[h * L_SEQ + p] : -__builtin_inff();
  const float s2 = c2 ? l2[h * L_SEQ + p] : -__builtin_inff();
  const float mx = fmaxf(s0, fmaxf(s1, s2));
  float w0 = __expf(s0 - mx);
  float w1 = c1 ? __expf(s1 - mx) : 0.f;
  float w2 = c2 ? __expf(s2 - mx) : 0.f;
  const float inv = 1.0f / (w0 + w1 + w2);
  w0 *= inv; w1 *= inv; w2 *= inv;

  const size_t off = (size_t)p * EDIM + h * 64 + dc * 8;
  float acc[8];
  bf16x8 a0 = *(const bf16x8*)(o0 + off);
#pragma unroll
  for (int j = 0; j < 8; j++) acc[j] = w0 * (float)a0[j];
  if (c1) {
    bf16x8 a1 = *(const bf16x8*)(o1 + off);
#pragma unroll
    for (int j = 0; j < 8; j++) acc[j] += w1 * (float)a1[j];
  }
  if (c2) {
    bf16x8 a2 = *(const bf16x8*)(o2 + off);
#pragma unroll
    for (int j = 0; j < 8; j++) acc[j] += w2 * (float)a2[j];
  }
  bf16x8 r;
#pragma unroll
  for (int j = 0; j < 8; j++) r[j] = (bf16)acc[j];
  *(bf16x8*)(merged + off) = r;
}

// ---------------------------------------------------------------------------
extern "C" void kernel_launch(void* const* d_in, const int* in_sizes, int n_in,
                              void* d_out, int out_size, void* d_ws, size_t ws_size,
                              hipStream_t stream)
{
  (void)in_sizes; (void)n_in; (void)out_size; (void)ws_size;
  const float* query = (const float*)d_in[0];
  const float* key   = (const float*)d_in[1];
  const float* value = (const float*)d_in[2];
  const float* Wq = (const float*)d_in[3];
  const float* bq = (const float*)d_in[4];
  const float* Wk = (const float*)d_in[5];
  const float* bk = (const float*)d_in[6];
  const float* Wv = (const float*)d_in[7];
  const float* bv = (const float*)d_in[8];
  const float* Wo = (const float*)d_in[9];
  const float* bo = (const float*)d_in[10];

  char* base = (char*)d_ws;
  size_t off = 0;
  auto take = [&](size_t nbytes) -> char* {
    char* p = base + off;
    off += (nbytes + 255) & ~(size_t)255;
    return p;
  };
  const size_t LE2 = (size_t)L_SEQ * EDIM * 2;
  const size_t EE2 = (size_t)EDIM * EDIM * 2;
  bf16* xq  = (bf16*)take(LE2);
  bf16* xk  = (bf16*)take(LE2);
  bf16* xv  = (bf16*)take(LE2);
  bf16* wqb = (bf16*)take(EE2);
  bf16* wkb = (bf16*)take(EE2);
  bf16* wvb = (bf16*)take(EE2);
  bf16* wob = (bf16*)take(EE2);
  bf16* qb  = (bf16*)take(LE2);
  bf16* kb  = (bf16*)take(LE2);
  bf16* vt0 = (bf16*)take((size_t)4 * NH * HD * GLEN * 2);
  bf16* vt1 = (bf16*)take((size_t)2 * NH * HD * GLEN * 2);
  bf16* vt2 = (bf16*)take((size_t)1 * NH * HD * GLEN * 2);
  float* lse0 = (float*)take((size_t)NH * L_SEQ * 4);
  float* lse1 = (float*)take((size_t)NH * L_SEQ * 4);
  float* lse2 = (float*)take((size_t)NH * L_SEQ * 4);
  bf16* merged = (bf16*)take(LE2);
  // branch outputs alias the converted inputs (dead after gemm_qkv)
  bf16* o0 = xq; bf16* o1 = xk; bf16* o2 = xv;

  dim3 blk(256);
  cvt_kernel<<<dim3(8192), blk, 0, stream>>>(
      query, key, value, Wq, Wk, Wv, Wo, xq, xk, xv, wqb, wkb, wvb, wob);
  gemm_qkv_kernel<<<dim3(8, 32, 3), blk, 0, stream>>>(
      xq, xk, xv, wqb, wkb, wvb, bq, bk, bv, qb, kb, vt0, vt1, vt2);
  attn_kernel<<<dim3(896), blk, 0, stream>>>(
      qb, kb, vt0, vt1, vt2, o0, o1, o2, lse0, lse1, lse2);
  merge_kernel<<<dim3(2048), blk, 0, stream>>>(
      o0, o1, o2, lse0, lse1, lse2, merged);
  gemm_out_kernel<<<dim3(8, 32), blk, 0, stream>>>(merged, wob, bo, (float*)d_out);
}